// Round 3
// baseline (52425.879 us; speedup 1.0000x reference)
//
#include <hip/hip_runtime.h>

// ---------------------------------------------------------------------------
// KokoroModel: emb -> biLSTM enc -> proj -> dur MLP -> length-regulate ->
//              MHA (teacher-forced) -> dec LSTM -> mel proj
// B=8, T_TEXT=256, T_MEL=1024, H=512, MEL=80, NH=8, HD=64 — all fp32.
// Round 3: persistent LSTM scans (weights in VGPRs, spin barriers) replace
// 1280 per-timestep launches; GEMM uses float4/ds_read_b128 micro-tiles.
// ---------------------------------------------------------------------------

typedef unsigned short u16;
typedef unsigned int u32;

#define BB 8
#define TT 256
#define TM 1024
#define HH 512
#define MELC 80
#define G4 2048   // 4*H

__device__ __forceinline__ float sigmoidf_(float x) { return 1.f / (1.f + __expf(-x)); }

// ------------------------- workspace layout (floats) -----------------------
// scan region: enc hbuf [2][2][8][512]=16384 | dec hbuf [2][8][512]=8192 |
//              barrier counters 24 groups x 32 ints
#define O_ENCH    0u
#define O_DECH    16384u
#define O_CNT     24576u            /* ints, 24*32 */
#define O_LOGDUR  36864u
#define O_KIDX    38912u            /* 8192 ints */
#define O_ENC     47104u            /* 2048x512 */
#define O_R1      1095680u          /* 4M: hf|hb|cat  -> exp -> ctx */
#define O_ATT     5289984u          /* 4M attended */
#define O_QIN     9484288u          /* 4M q_in */
#define O_BIG2    13678592u         /* 8M: q|k -> dec_in -> h_dec|mel_f */
#define O_BIG1    22067200u         /* 16.8M: xg_f|xg_b|x -> h1|h2|v|mel_in -> xg_dec */
// sub-offsets
#define O_HF      (O_R1)
#define O_HB      (O_R1 + 1048576u)
#define O_CAT     (O_R1 + 2097152u)
#define O_EXP     (O_R1)
#define O_CTX     (O_R1)
#define O_Q       (O_BIG2)
#define O_K       (O_BIG2 + 4194304u)
#define O_DECIN   (O_BIG2)
#define O_HDEC    (O_BIG2)
#define O_MELF    (O_BIG2 + 4194304u)
#define O_XGF     (O_BIG1)
#define O_XGB     (O_BIG1 + 4194304u)
#define O_X       (O_BIG1 + 8388608u)
#define O_H1      (O_BIG1 + 8388608u)
#define O_H2      (O_BIG1 + 9437184u)
#define O_V       (O_BIG1 + 10485760u)
#define O_MELIN   (O_BIG1 + 14680064u)
#define O_XGD     (O_BIG1)

// ---------------------------------------------------------------------------
__global__ __launch_bounds__(256) void zero_kernel(float* p, int n) {
    int i = blockIdx.x * 256 + threadIdx.x;
    if (i < n) p[i] = 0.f;
}

__global__ __launch_bounds__(256) void embed_kernel(const int* idx, const float* emb, float* x) {
    int i = blockIdx.x * 256 + threadIdx.x;      // over 2048*512
    int tok = i >> 9, h = i & 511;
    x[i] = emb[(size_t)idx[tok] * HH + h];
}

// C[M,N] = act(A[M,K] @ W[N,K]^T + bias[N]);  all fp32.
// 128x128 tile, BK=16, 256 threads, 8x8 micro-tile in 2x2 float4 fragments.
// Requires: M%128==0, K%16==0, N%4==0 (guards only on N).
template <int ACT>
__global__ __launch_bounds__(256) void gemm_bt(const float* __restrict__ A,
                                               const float* __restrict__ W,
                                               const float* __restrict__ bias,
                                               float* __restrict__ C,
                                               int M, int N, int K) {
    __shared__ float As[16][132];
    __shared__ float Ws[16][132];
    const int bm = blockIdx.y * 128, bn = blockIdx.x * 128;
    const int tid = threadIdx.x;
    const int tx = tid & 15, ty = tid >> 4;
    float acc[64];                               // [(ih*2+jh)*16 + ii*4 + jj]
#pragma unroll
    for (int i = 0; i < 64; i++) acc[i] = 0.f;

    for (int k0 = 0; k0 < K; k0 += 16) {
#pragma unroll
        for (int q = 0; q < 2; q++) {
            int fid = tid * 2 + q;               // 0..511
            int m = fid >> 2, kq = (fid & 3) << 2;
            float4 va = *(const float4*)(A + (size_t)(bm + m) * K + k0 + kq);
            As[kq + 0][m] = va.x; As[kq + 1][m] = va.y;
            As[kq + 2][m] = va.z; As[kq + 3][m] = va.w;
            float4 vw = make_float4(0.f, 0.f, 0.f, 0.f);
            if (bn + m < N) vw = *(const float4*)(W + (size_t)(bn + m) * K + k0 + kq);
            Ws[kq + 0][m] = vw.x; Ws[kq + 1][m] = vw.y;
            Ws[kq + 2][m] = vw.z; Ws[kq + 3][m] = vw.w;
        }
        __syncthreads();
#pragma unroll
        for (int kk = 0; kk < 16; kk++) {
            float4 a0 = *(const float4*)&As[kk][ty * 4];
            float4 a1 = *(const float4*)&As[kk][64 + ty * 4];
            float4 b0 = *(const float4*)&Ws[kk][tx * 4];
            float4 b1 = *(const float4*)&Ws[kk][64 + tx * 4];
            float av[8] = {a0.x, a0.y, a0.z, a0.w, a1.x, a1.y, a1.z, a1.w};
            float bv[8] = {b0.x, b0.y, b0.z, b0.w, b1.x, b1.y, b1.z, b1.w};
#pragma unroll
            for (int ih = 0; ih < 2; ih++)
#pragma unroll
                for (int ii = 0; ii < 4; ii++) {
                    float a = av[ih * 4 + ii];
#pragma unroll
                    for (int jh = 0; jh < 2; jh++)
#pragma unroll
                        for (int jjv = 0; jjv < 4; jjv++)
                            acc[(ih * 2 + jh) * 16 + ii * 4 + jjv] =
                                fmaf(a, bv[jh * 4 + jjv], acc[(ih * 2 + jh) * 16 + ii * 4 + jjv]);
                }
        }
        __syncthreads();
    }
#pragma unroll
    for (int ih = 0; ih < 2; ih++)
#pragma unroll
        for (int jh = 0; jh < 2; jh++) {
            int n = bn + jh * 64 + tx * 4;
            if (n >= N) continue;
            float4 bb = make_float4(0.f, 0.f, 0.f, 0.f);
            if (bias) bb = *(const float4*)(bias + n);
#pragma unroll
            for (int ii = 0; ii < 4; ii++) {
                int m = bm + ih * 64 + ty * 4 + ii;
                float4 o;
                o.x = acc[(ih * 2 + jh) * 16 + ii * 4 + 0] + bb.x;
                o.y = acc[(ih * 2 + jh) * 16 + ii * 4 + 1] + bb.y;
                o.z = acc[(ih * 2 + jh) * 16 + ii * 4 + 2] + bb.z;
                o.w = acc[(ih * 2 + jh) * 16 + ii * 4 + 3] + bb.w;
                if (ACT == 1) {
                    o.x = fmaxf(o.x, 0.f); o.y = fmaxf(o.y, 0.f);
                    o.z = fmaxf(o.z, 0.f); o.w = fmaxf(o.w, 0.f);
                }
                *(float4*)(C + (size_t)m * N + n) = o;
            }
        }
}

// ---------------------------------------------------------------------------
// Persistent LSTM scan. One wave owns 16 gate-rows (4 j x 4 gates) for one
// (dir,batch); lane = ks(0..3)*16 + rl(0..15), rl = gate*4+jj. 128 W_hh floats
// per lane live in VGPRs for the whole scan. Cross-wg h broadcast via global
// ping-pong buffers + per-group spin barrier (32 wgs/group, device atomics).
// grid = ndir*8*32 wgs of 256 threads; all co-resident (<=2 wg/CU needed).
__global__ __launch_bounds__(256, 2) void lstm_scan(
    const float* __restrict__ xg0, const float* __restrict__ xg1,
    const float* __restrict__ whh0, const float* __restrict__ whh1,
    const float* __restrict__ bhh0, const float* __restrict__ bhh1,
    float* hbuf, float* hout0, float* hout1,
    int* cnts, int T, int ndir, int cntBase) {
    const int wg = blockIdx.x;
    const int group = wg >> 5;                   // (dir*8 + b) or b
    const int dir = (ndir == 2) ? (group >> 3) : 0;
    const int b = group & 7;
    const int wave = threadIdx.x >> 6;
    const int lane = threadIdx.x & 63;
    const int ks = lane >> 4;                    // k-slice 0..3 (128 each)
    const int rl = lane & 15;                    // gate*4 + jj
    const int jj = rl & 3;
    const int jb = (wg & 31) * 4 + wave;         // 0..127
    const int row = (rl >> 2) * HH + jb * 4 + jj;
    const int j = jb * 4 + jj;

    const float* xg  = dir ? xg1 : xg0;
    const float* whh = dir ? whh1 : whh0;
    const float* bhh = dir ? bhh1 : bhh0;
    float* hout = dir ? hout1 : hout0;
    int* cnt = cnts + (cntBase + group) * 32;

    float4 wv[32];
    const float4* wp = (const float4*)(whh + (size_t)row * HH + ks * 128);
#pragma unroll
    for (int i = 0; i < 32; i++) wv[i] = wp[i];
    const float xb = bhh[row];
    float c_ = 0.f;

    for (int t = 0; t < T; t++) {
        const int te = dir ? (T - 1 - t) : t;
        const float4* hp4 = (const float4*)(hbuf +
            ((size_t)(((t + 1) & 1) * ndir + dir) * 8 + b) * HH + ks * 128);
        float acc = 0.f;
#pragma unroll
        for (int i = 0; i < 32; i++) {
            float4 h4 = hp4[i];
            acc = fmaf(wv[i].x, h4.x, acc);
            acc = fmaf(wv[i].y, h4.y, acc);
            acc = fmaf(wv[i].z, h4.z, acc);
            acc = fmaf(wv[i].w, h4.w, acc);
        }
        if (ks == 0) acc += xg[(size_t)(b * T + te) * G4 + row] + xb;
        acc += __shfl_xor(acc, 16);              // sum k-slices
        acc += __shfl_xor(acc, 32);
        float gI = __shfl(acc, jj);
        float gF = __shfl(acc, 4 + jj);
        float gG = __shfl(acc, 8 + jj);
        float gO = __shfl(acc, 12 + jj);
        if (lane < 4) {                          // producer lanes: jj == lane
            float i_ = sigmoidf_(gI), f_ = sigmoidf_(gF);
            float g_ = tanhf(gG),     o_ = sigmoidf_(gO);
            c_ = f_ * c_ + i_ * g_;
            float h_ = o_ * tanhf(c_);
            float* hw = hbuf + ((size_t)((t & 1) * ndir + dir) * 8 + b) * HH;
            hw[j] = h_;
            hout[(size_t)(b * T + te) * HH + j] = h_;
        }
        __threadfence();                         // release: drain h stores to L2
        __syncthreads();
        if (threadIdx.x == 0) {
            __hip_atomic_fetch_add(cnt, 1, __ATOMIC_RELAXED, __HIP_MEMORY_SCOPE_AGENT);
            const int target = 32 * (t + 1);
            while (__hip_atomic_load(cnt, __ATOMIC_RELAXED, __HIP_MEMORY_SCOPE_AGENT) < target)
                __builtin_amdgcn_s_sleep(1);
        }
        __syncthreads();
        __threadfence();                         // acquire: invalidate L1
    }
}

__global__ __launch_bounds__(256) void cat_kernel(const float* hf, const float* hb, float* cat) {
    int i = blockIdx.x * 256 + threadIdx.x;      // over 2048*1024
    int row = i >> 10, h = i & 1023;
    cat[i] = (h < HH) ? hf[(size_t)row * HH + h] : hb[(size_t)row * HH + h - HH];
}

__global__ __launch_bounds__(256) void dur3_kernel(const float* __restrict__ h2,
                                                   const float* __restrict__ w,
                                                   const float* __restrict__ b, float* out) {
    int row = blockIdx.x * 256 + threadIdx.x;    // 2048
    float acc = b[0];
    const float* hp = h2 + (size_t)row * 256;
    for (int k = 0; k < 256; k++) acc += hp[k] * w[k];
    out[row] = acc;
}

// durations -> cumsum -> searchsorted index per mel position (-1 = pad)
__global__ __launch_bounds__(256) void length_reg_kernel(const float* __restrict__ dur, int* kidx) {
    int b = blockIdx.x;
    int t = threadIdx.x;
    __shared__ int cum[256];
    cum[t] = (int)rintf(dur[b * TT + t]);
    __syncthreads();
    for (int off = 1; off < 256; off <<= 1) {
        int val = (t >= off) ? cum[t - off] : 0;
        __syncthreads();
        cum[t] += val;
        __syncthreads();
    }
    int total = cum[255];
    for (int pos = t; pos < TM; pos += 256) {
        int lo = 0, hi = 256;
        while (lo < hi) {
            int mid = (lo + hi) >> 1;
            if (cum[mid] <= pos) lo = mid + 1; else hi = mid;
        }
        int idx = (pos < total) ? ((lo < 255) ? lo : 255) : -1;
        kidx[b * TM + pos] = idx;
    }
}

__global__ __launch_bounds__(256) void expand_kernel(const float* __restrict__ enc,
                                                     const int* __restrict__ kidx, float* exp_) {
    int i = blockIdx.x * 256 + threadIdx.x;      // over 8192*512
    int row = i >> 9, h = i & 511;               // row = b*1024 + pos
    int b = row >> 10;
    int id = kidx[row];
    exp_[i] = (id >= 0) ? enc[(size_t)(b * TT + id) * HH + h] : 0.f;
}

__global__ __launch_bounds__(256) void melin_kernel(const float* __restrict__ mel, float* mel_in) {
    int i = blockIdx.x * 256 + threadIdx.x;      // over 8192*80
    if (i >= BB * TM * MELC) return;
    int row = i / MELC, cc = i - row * MELC;
    int b = row >> 10, tpos = row & 1023;
    mel_in[i] = (tpos == 0) ? 0.f : mel[(size_t)(b * TM + tpos - 1) * MELC + cc];
}

// Flash-style MHA: one q-row per thread; K/V tiles (32x64) in LDS.
__global__ __launch_bounds__(256) void attn_kernel(const float* __restrict__ q,
                                                   const float* __restrict__ k,
                                                   const float* __restrict__ v,
                                                   const int* __restrict__ kidx,
                                                   float* __restrict__ ctx) {
    const int bh = blockIdx.y;
    const int b = bh >> 3, h = bh & 7;
    const int qrow = blockIdx.x * 256 + threadIdx.x;
    __shared__ float Ks[32][64];
    __shared__ float Vs[32][64];
    __shared__ float spad[32];

    float qr[64], acc[64];
    const float* qp = q + (size_t)(b * TM + qrow) * HH + h * 64;
#pragma unroll
    for (int d = 0; d < 64; d++) qr[d] = qp[d] * 0.125f;
#pragma unroll
    for (int d = 0; d < 64; d++) acc[d] = 0.f;
    float m = -1e30f, l = 0.f;

    for (int k0 = 0; k0 < TM; k0 += 32) {
        __syncthreads();
#pragma unroll
        for (int i = 0; i < 8; i++) {
            int idx = threadIdx.x + i * 256;     // 0..2047
            int r = idx >> 6, d = idx & 63;
            size_t off = (size_t)(b * TM + k0 + r) * HH + h * 64 + d;
            Ks[r][d] = k[off];
            Vs[r][d] = v[off];
        }
        if (threadIdx.x < 32)
            spad[threadIdx.x] = (kidx[b * TM + k0 + threadIdx.x] < 0) ? 1.f : 0.f;
        __syncthreads();
        for (int r = 0; r < 32; r++) {
            float s = 0.f;
#pragma unroll
            for (int d = 0; d < 64; d++) s += qr[d] * Ks[r][d];
            if (spad[r] != 0.f) s = -1e9f;
            float mn = fmaxf(m, s);
            float corr = __expf(m - mn);
            float p = __expf(s - mn);
            l = l * corr + p;
#pragma unroll
            for (int d = 0; d < 64; d++) acc[d] = acc[d] * corr + p * Vs[r][d];
            m = mn;
        }
    }
    float inv = 1.f / l;
    float* op = ctx + (size_t)(b * TM + qrow) * HH + h * 64;
#pragma unroll
    for (int d = 0; d < 64; d++) op[d] = acc[d] * inv;
}

__global__ __launch_bounds__(256) void decin_kernel(const float* q_in, const float* att, float* dec_in) {
    int i = blockIdx.x * 256 + threadIdx.x;      // over 8192*1024
    int row = i >> 10, h = i & 1023;
    dec_in[i] = (h < HH) ? q_in[(size_t)row * HH + h] : att[(size_t)row * HH + h - HH];
}

__global__ __launch_bounds__(256) void finalize_kernel(const float* melf, const float* logdur, float* out) {
    int i = blockIdx.x * 256 + threadIdx.x;
    if (i < BB * TM * MELC) out[i] = melf[i];
    else if (i < BB * TM * MELC + BB * TT) out[i] = logdur[i - BB * TM * MELC];
}

// ---------------------------------------------------------------------------
extern "C" void kernel_launch(void* const* d_in, const int* in_sizes, int n_in,
                              void* d_out, int out_size, void* d_ws, size_t ws_size,
                              hipStream_t stream) {
    const int*   ph      = (const int*)d_in[0];
    const float* mel     = (const float*)d_in[1];
    const float* durs    = (const float*)d_in[2];
    const float* emb     = (const float*)d_in[3];
    const float* w_ih_f  = (const float*)d_in[4];
    const float* w_hh_f  = (const float*)d_in[5];
    const float* b_ih_f  = (const float*)d_in[6];
    const float* b_hh_f  = (const float*)d_in[7];
    const float* w_ih_b  = (const float*)d_in[8];
    const float* w_hh_b  = (const float*)d_in[9];
    const float* b_ih_b  = (const float*)d_in[10];
    const float* b_hh_b  = (const float*)d_in[11];
    const float* proj_w  = (const float*)d_in[12];
    const float* proj_b  = (const float*)d_in[13];
    const float* dur_w1  = (const float*)d_in[14];
    const float* dur_b1  = (const float*)d_in[15];
    const float* dur_w2  = (const float*)d_in[16];
    const float* dur_b2  = (const float*)d_in[17];
    const float* dur_w3  = (const float*)d_in[18];
    const float* dur_b3  = (const float*)d_in[19];
    const float* melin_w = (const float*)d_in[20];
    const float* melin_b = (const float*)d_in[21];
    const float* attin_w = (const float*)d_in[22];
    const float* attin_b = (const float*)d_in[23];
    const float* atout_w = (const float*)d_in[24];
    const float* atout_b = (const float*)d_in[25];
    const float* dec_wih = (const float*)d_in[26];
    const float* dec_whh = (const float*)d_in[27];
    const float* dec_bih = (const float*)d_in[28];
    const float* dec_bhh = (const float*)d_in[29];
    const float* melo_w  = (const float*)d_in[30];
    const float* melo_b  = (const float*)d_in[31];

    float* ws = (float*)d_ws;
    int*   kidx = (int*)(ws + O_KIDX);
    int*   cnts = (int*)(ws + O_CNT);

    dim3 b256(256);
    auto gemm = [&](const float* A, const float* W, const float* bias, float* C,
                    int M, int N, int K, int act) {
        dim3 g((N + 127) / 128, (M + 127) / 128);
        if (act) gemm_bt<1><<<g, b256, 0, stream>>>(A, W, bias, C, M, N, K);
        else     gemm_bt<0><<<g, b256, 0, stream>>>(A, W, bias, C, M, N, K);
    };

    // 0) zero scan h-buffers + barrier counters (ws is poisoned each call)
    zero_kernel<<<100, b256, 0, stream>>>(ws, 25600);

    // 1) embedding -> x [2048,512]
    embed_kernel<<<(2048 * 512) / 256, b256, 0, stream>>>(ph, emb, ws + O_X);

    // 2) encoder xg = x@W_ih^T + b_ih  [2048,2048] per dir
    gemm(ws + O_X, w_ih_f, b_ih_f, ws + O_XGF, 2048, G4, HH, 0);
    gemm(ws + O_X, w_ih_b, b_ih_b, ws + O_XGB, 2048, G4, HH, 0);

    // 3) encoder scans: fwd+bwd in ONE persistent launch (512 wgs)
    lstm_scan<<<512, b256, 0, stream>>>(ws + O_XGF, ws + O_XGB,
                                        w_hh_f, w_hh_b, b_hh_f, b_hh_b,
                                        ws + O_ENCH, ws + O_HF, ws + O_HB,
                                        cnts, TT, 2, 0);

    // 4) proj([hf,hb]) -> enc [2048,512]
    cat_kernel<<<(2048 * 1024) / 256, b256, 0, stream>>>(ws + O_HF, ws + O_HB, ws + O_CAT);
    gemm(ws + O_CAT, proj_w, proj_b, ws + O_ENC, 2048, HH, 2 * HH, 0);

    // 5) duration predictor
    gemm(ws + O_ENC, dur_w1, dur_b1, ws + O_H1, 2048, HH, HH, 1);
    gemm(ws + O_H1, dur_w2, dur_b2, ws + O_H2, 2048, 256, HH, 1);
    dur3_kernel<<<8, b256, 0, stream>>>(ws + O_H2, dur_w3, dur_b3, ws + O_LOGDUR);

    // 6) length regulation
    length_reg_kernel<<<8, b256, 0, stream>>>(durs, kidx);
    expand_kernel<<<(8192 * 512) / 256, b256, 0, stream>>>(ws + O_ENC, kidx, ws + O_EXP);

    // 7) q_in = Linear(mel shifted) [8192,512]
    melin_kernel<<<(8192 * MELC + 255) / 256, b256, 0, stream>>>(mel, ws + O_MELIN);
    gemm(ws + O_MELIN, melin_w, melin_b, ws + O_QIN, 8192, HH, MELC, 0);

    // 8) q,k,v projections (attn_in_w rows: [wq;wk;wv])
    gemm(ws + O_QIN, attin_w,              attin_b,        ws + O_Q, 8192, HH, HH, 0);
    gemm(ws + O_EXP, attin_w + 512 * 512,  attin_b + 512,  ws + O_K, 8192, HH, HH, 0);
    gemm(ws + O_EXP, attin_w + 1024 * 512, attin_b + 1024, ws + O_V, 8192, HH, HH, 0);

    // 9) attention -> ctx; out projection -> attended
    attn_kernel<<<dim3(4, 64), b256, 0, stream>>>(ws + O_Q, ws + O_K, ws + O_V, kidx, ws + O_CTX);
    gemm(ws + O_CTX, atout_w, atout_b, ws + O_ATT, 8192, HH, HH, 0);

    // 10) decoder: dec_in = [q_in, attended]; xg = dec_in@W_ih^T + b_ih
    decin_kernel<<<(8192 * 1024) / 256, b256, 0, stream>>>(ws + O_QIN, ws + O_ATT, ws + O_DECIN);
    gemm(ws + O_DECIN, dec_wih, dec_bih, ws + O_XGD, 8192, G4, 2 * HH, 0);

    // 11) decoder scan: ONE persistent launch (256 wgs, 1024 steps)
    lstm_scan<<<256, b256, 0, stream>>>(ws + O_XGD, ws + O_XGD,
                                        dec_whh, dec_whh, dec_bhh, dec_bhh,
                                        ws + O_DECH, ws + O_HDEC, ws + O_HDEC,
                                        cnts, TM, 1, 16);

    // 12) mel projection + pack outputs
    gemm(ws + O_HDEC, melo_w, melo_b, ws + O_MELF, 8192, MELC, HH, 0);
    finalize_kernel<<<(BB * TM * MELC + BB * TT + 255) / 256, b256, 0, stream>>>(
        ws + O_MELF, ws + O_LOGDUR, (float*)d_out);
}

// Round 4
// 27158.554 us; speedup vs baseline: 1.9304x; 1.9304x over previous
//
#include <hip/hip_runtime.h>

// ---------------------------------------------------------------------------
// KokoroModel: emb -> biLSTM enc -> proj -> dur MLP -> length-regulate ->
//              MHA (teacher-forced) -> dec LSTM -> mel proj
// B=8, T_TEXT=256, T_MEL=1024, H=512, MEL=80, NH=8, HD=64 — all fp32.
// Round 4: fence-free persistent LSTM scans. Cross-wg h exchange via sc1
// (agent-scope relaxed) atomics — NO __threadfence (which emits whole-L2
// wbl2/inv on gfx950 and caused the round-3 50µs/step collapse). Weights
// dedup'd across batch: dec=32 wgs, enc=64 wgs, W_hh slices in VGPRs.
// ---------------------------------------------------------------------------

typedef unsigned short u16;
typedef unsigned int u32;

#define BB 8
#define TT 256
#define TM 1024
#define HH 512
#define MELC 80
#define G4 2048   // 4*H

__device__ __forceinline__ float sigmoidf_(float x) { return 1.f / (1.f + __expf(-x)); }

// ------------------------- workspace layout (floats) -----------------------
// O_ENCH: enc h ping-pong [2 groups][2 slots][8][512] = 16384
// O_DECH: dec h ping-pong [2 slots][8][512] = 8192
// O_CNT : flags, 3 groups x 32 ints (enc f, enc b, dec)
#define O_ENCH    0u
#define O_DECH    16384u
#define O_CNT     24576u            /* ints, 3*32 */
#define O_LOGDUR  36864u
#define O_KIDX    38912u            /* 8192 ints */
#define O_ENC     47104u            /* 2048x512 */
#define O_R1      1095680u          /* 4M: hf|hb|cat  -> exp -> ctx */
#define O_ATT     5289984u          /* 4M attended */
#define O_QIN     9484288u          /* 4M q_in */
#define O_BIG2    13678592u         /* 8M: q|k -> dec_in -> h_dec|mel_f */
#define O_BIG1    22067200u         /* 16.8M: xg_f|xg_b|x -> h1|h2|v|mel_in -> xg_dec */
// sub-offsets
#define O_HF      (O_R1)
#define O_HB      (O_R1 + 1048576u)
#define O_CAT     (O_R1 + 2097152u)
#define O_EXP     (O_R1)
#define O_CTX     (O_R1)
#define O_Q       (O_BIG2)
#define O_K       (O_BIG2 + 4194304u)
#define O_DECIN   (O_BIG2)
#define O_HDEC    (O_BIG2)
#define O_MELF    (O_BIG2 + 4194304u)
#define O_XGF     (O_BIG1)
#define O_XGB     (O_BIG1 + 4194304u)
#define O_X       (O_BIG1 + 8388608u)
#define O_H1      (O_BIG1 + 8388608u)
#define O_H2      (O_BIG1 + 9437184u)
#define O_V       (O_BIG1 + 10485760u)
#define O_MELIN   (O_BIG1 + 14680064u)
#define O_XGD     (O_BIG1)

// ---------------------------------------------------------------------------
__global__ __launch_bounds__(256) void zero_kernel(float* p, int n) {
    int i = blockIdx.x * 256 + threadIdx.x;
    if (i < n) p[i] = 0.f;
}

__global__ __launch_bounds__(256) void embed_kernel(const int* idx, const float* emb, float* x) {
    int i = blockIdx.x * 256 + threadIdx.x;      // over 2048*512
    int tok = i >> 9, h = i & 511;
    x[i] = emb[(size_t)idx[tok] * HH + h];
}

// C[M,N] = act(A[M,K] @ W[N,K]^T + bias[N]);  all fp32.
// 128x128 tile, BK=16, 256 threads, 8x8 micro-tile in 2x2 float4 fragments.
template <int ACT>
__global__ __launch_bounds__(256) void gemm_bt(const float* __restrict__ A,
                                               const float* __restrict__ W,
                                               const float* __restrict__ bias,
                                               float* __restrict__ C,
                                               int M, int N, int K) {
    __shared__ float As[16][132];
    __shared__ float Ws[16][132];
    const int bm = blockIdx.y * 128, bn = blockIdx.x * 128;
    const int tid = threadIdx.x;
    const int tx = tid & 15, ty = tid >> 4;
    float acc[64];
#pragma unroll
    for (int i = 0; i < 64; i++) acc[i] = 0.f;

    for (int k0 = 0; k0 < K; k0 += 16) {
#pragma unroll
        for (int q = 0; q < 2; q++) {
            int fid = tid * 2 + q;               // 0..511
            int m = fid >> 2, kq = (fid & 3) << 2;
            float4 va = *(const float4*)(A + (size_t)(bm + m) * K + k0 + kq);
            As[kq + 0][m] = va.x; As[kq + 1][m] = va.y;
            As[kq + 2][m] = va.z; As[kq + 3][m] = va.w;
            float4 vw = make_float4(0.f, 0.f, 0.f, 0.f);
            if (bn + m < N) vw = *(const float4*)(W + (size_t)(bn + m) * K + k0 + kq);
            Ws[kq + 0][m] = vw.x; Ws[kq + 1][m] = vw.y;
            Ws[kq + 2][m] = vw.z; Ws[kq + 3][m] = vw.w;
        }
        __syncthreads();
#pragma unroll
        for (int kk = 0; kk < 16; kk++) {
            float4 a0 = *(const float4*)&As[kk][ty * 4];
            float4 a1 = *(const float4*)&As[kk][64 + ty * 4];
            float4 b0 = *(const float4*)&Ws[kk][tx * 4];
            float4 b1 = *(const float4*)&Ws[kk][64 + tx * 4];
            float av[8] = {a0.x, a0.y, a0.z, a0.w, a1.x, a1.y, a1.z, a1.w};
            float bv[8] = {b0.x, b0.y, b0.z, b0.w, b1.x, b1.y, b1.z, b1.w};
#pragma unroll
            for (int ih = 0; ih < 2; ih++)
#pragma unroll
                for (int ii = 0; ii < 4; ii++) {
                    float a = av[ih * 4 + ii];
#pragma unroll
                    for (int jh = 0; jh < 2; jh++)
#pragma unroll
                        for (int jjv = 0; jjv < 4; jjv++)
                            acc[(ih * 2 + jh) * 16 + ii * 4 + jjv] =
                                fmaf(a, bv[jh * 4 + jjv], acc[(ih * 2 + jh) * 16 + ii * 4 + jjv]);
                }
        }
        __syncthreads();
    }
#pragma unroll
    for (int ih = 0; ih < 2; ih++)
#pragma unroll
        for (int jh = 0; jh < 2; jh++) {
            int n = bn + jh * 64 + tx * 4;
            if (n >= N) continue;
            float4 bb = make_float4(0.f, 0.f, 0.f, 0.f);
            if (bias) bb = *(const float4*)(bias + n);
#pragma unroll
            for (int ii = 0; ii < 4; ii++) {
                int m = bm + ih * 64 + ty * 4 + ii;
                float4 o;
                o.x = acc[(ih * 2 + jh) * 16 + ii * 4 + 0] + bb.x;
                o.y = acc[(ih * 2 + jh) * 16 + ii * 4 + 1] + bb.y;
                o.z = acc[(ih * 2 + jh) * 16 + ii * 4 + 2] + bb.z;
                o.w = acc[(ih * 2 + jh) * 16 + ii * 4 + 3] + bb.w;
                if (ACT == 1) {
                    o.x = fmaxf(o.x, 0.f); o.y = fmaxf(o.y, 0.f);
                    o.z = fmaxf(o.z, 0.f); o.w = fmaxf(o.w, 0.f);
                }
                *(float4*)(C + (size_t)m * N + n) = o;
            }
        }
}

// ---------------------------------------------------------------------------
// Persistent fence-free LSTM scan. 32 wgs per (dir) group; wg owns j-range
// [wgi*16, wgi*16+16) x 4 gates for ALL 8 batches. Wave w: j-quad jq =
// wgi*16+w*4. Lane = ks(0..15)*4 + gate(0..3); weights W_hh[gate*512+jq+jj]
// [ks*32..+32) in VGPRs (32 float4/lane). Per step: h_prev staged LDS
// (bank-rotated), dot + shfl_xor ks-reduce + shfl gate-gather, c replicated.
// Cross-wg: sc1 (agent relaxed) stores/loads only — NO fences. Barrier =
// per-wg flag array + ballot poll.
__global__ __launch_bounds__(256, 1) void lstm_scan(
    const float* __restrict__ xg0, const float* __restrict__ xg1,
    const float* __restrict__ whh0, const float* __restrict__ whh1,
    const float* __restrict__ bhh0, const float* __restrict__ bhh1,
    float* hbuf, float* hout0, float* hout1,
    int* flags, int T, int ndir) {
    const int wg = blockIdx.x;
    const int group = wg >> 5;                   // dir (or 0)
    const int wgi = wg & 31;
    const int dir = (ndir == 2) ? group : 0;
    const float* xg  = dir ? xg1 : xg0;
    const float* whh = dir ? whh1 : whh0;
    const float* bhh = dir ? bhh1 : bhh0;
    float* hout = dir ? hout1 : hout0;
    float* hb = hbuf + group * 8192;             // [2 slots][8][512]
    int* flg = flags + group * 32;

    const int wave = threadIdx.x >> 6;
    const int lane = threadIdx.x & 63;
    const int gate = lane & 3;
    const int ks = lane >> 2;                    // k-slice of 32
    const int jq = wgi * 16 + wave * 4;

    // weights: wv[jj][i4] = W_hh[gate*512 + jq+jj][ks*32 + i4*4 ..+4)
    float4 wv[4][8];
#pragma unroll
    for (int jj = 0; jj < 4; jj++) {
        const float4* wp = (const float4*)(whh + (size_t)(gate * HH + jq + jj) * HH + ks * 32);
#pragma unroll
        for (int i = 0; i < 8; i++) wv[jj][i] = wp[i];
    }
    float xb0 = bhh[gate * HH + jq + 0];
    float xb1 = bhh[gate * HH + jq + 1];
    float xb2 = bhh[gate * HH + jq + 2];
    float xb3 = bhh[gate * HH + jq + 3];
    float cst[32];                               // c[b][jj], replicated all lanes
#pragma unroll
    for (int i = 0; i < 32; i++) cst[i] = 0.f;

    __shared__ float hs[4096];                   // staged h, bank-rotated

    for (int t = 0; t < T; t++) {
        const int te = dir ? (T - 1 - t) : t;
        // prefetch xg rows (only ks==0 lanes consume)
        float4 xgv[8];
        if (ks == 0) {
#pragma unroll
            for (int b = 0; b < 8; b++)
                xgv[b] = *(const float4*)(xg + (size_t)(b * T + te) * G4 + gate * HH + jq);
        }
        // stage h_prev from global (sc1) into LDS with bank rotation:
        // logical [b][k] -> lds[b*512 + (k&~31) + ((k + (k>>5)*4) & 31)]
        const float* hg = hb + ((t + 1) & 1) * 4096;
#pragma unroll
        for (int n = 0; n < 16; n++) {
            int idx = threadIdx.x + n * 256;
            int kk = idx & 511;
            float v = __hip_atomic_load(hg + idx, __ATOMIC_RELAXED, __HIP_MEMORY_SCOPE_AGENT);
            hs[(idx & ~511) + (kk & ~31) + (((kk & 31) + ((kk >> 5) << 2)) & 31)] = v;
        }
        __syncthreads();

        float hw_mine = 0.f;
#pragma unroll
        for (int b = 0; b < 8; b++) {
            float a0, a1, a2, a3;
            if (ks == 0) {
                a0 = xgv[b].x + xb0; a1 = xgv[b].y + xb1;
                a2 = xgv[b].z + xb2; a3 = xgv[b].w + xb3;
            } else { a0 = a1 = a2 = a3 = 0.f; }
#pragma unroll
            for (int i4 = 0; i4 < 8; i4++) {
                const float4 h4 = *(const float4*)
                    &hs[b * HH + ks * 32 + (((i4 + ks) & 7) << 2)];
                a0 = fmaf(wv[0][i4].x, h4.x, a0); a0 = fmaf(wv[0][i4].y, h4.y, a0);
                a0 = fmaf(wv[0][i4].z, h4.z, a0); a0 = fmaf(wv[0][i4].w, h4.w, a0);
                a1 = fmaf(wv[1][i4].x, h4.x, a1); a1 = fmaf(wv[1][i4].y, h4.y, a1);
                a1 = fmaf(wv[1][i4].z, h4.z, a1); a1 = fmaf(wv[1][i4].w, h4.w, a1);
                a2 = fmaf(wv[2][i4].x, h4.x, a2); a2 = fmaf(wv[2][i4].y, h4.y, a2);
                a2 = fmaf(wv[2][i4].z, h4.z, a2); a2 = fmaf(wv[2][i4].w, h4.w, a2);
                a3 = fmaf(wv[3][i4].x, h4.x, a3); a3 = fmaf(wv[3][i4].y, h4.y, a3);
                a3 = fmaf(wv[3][i4].z, h4.z, a3); a3 = fmaf(wv[3][i4].w, h4.w, a3);
            }
            // reduce over ks (lane bits 5:2)
            a0 += __shfl_xor(a0, 4);  a1 += __shfl_xor(a1, 4);
            a2 += __shfl_xor(a2, 4);  a3 += __shfl_xor(a3, 4);
            a0 += __shfl_xor(a0, 8);  a1 += __shfl_xor(a1, 8);
            a2 += __shfl_xor(a2, 8);  a3 += __shfl_xor(a3, 8);
            a0 += __shfl_xor(a0, 16); a1 += __shfl_xor(a1, 16);
            a2 += __shfl_xor(a2, 16); a3 += __shfl_xor(a3, 16);
            a0 += __shfl_xor(a0, 32); a1 += __shfl_xor(a1, 32);
            a2 += __shfl_xor(a2, 32); a3 += __shfl_xor(a3, 32);
            // gather 4 gates per jj; every lane computes all (b,jj)
            const int base = lane & ~3;
#pragma unroll
            for (int jj = 0; jj < 4; jj++) {
                float a = (jj == 0) ? a0 : (jj == 1) ? a1 : (jj == 2) ? a2 : a3;
                float gi = __shfl(a, base + 0);
                float gf = __shfl(a, base + 1);
                float gg = __shfl(a, base + 2);
                float go = __shfl(a, base + 3);
                float i_ = sigmoidf_(gi), f_ = sigmoidf_(gf);
                float G_ = tanhf(gg),     o_ = sigmoidf_(go);
                float cn = f_ * cst[b * 4 + jj] + i_ * G_;
                cst[b * 4 + jj] = cn;
                float hn = o_ * tanhf(cn);
                if (lane == b * 4 + jj) hw_mine = hn;
            }
        }
        // write h (sc1) + hout (normal); lanes 0..31: (b=lane>>2, jj=lane&3)
        if (lane < 32) {
            int b = lane >> 2, jj = lane & 3, j = jq + jj;
            __hip_atomic_store(hb + (t & 1) * 4096 + b * HH + j, hw_mine,
                               __ATOMIC_RELAXED, __HIP_MEMORY_SCOPE_AGENT);
            hout[(size_t)(b * T + te) * HH + j] = hw_mine;
        }
        __builtin_amdgcn_s_waitcnt(0);           // h stores acked (per wave)
        __syncthreads();
        if (threadIdx.x == 0)
            __hip_atomic_store(flg + wgi, t + 1, __ATOMIC_RELAXED, __HIP_MEMORY_SCOPE_AGENT);
        if (wave == 0) {
            const int need = t + 1;
            int it = 0;
            while (true) {
                int v = (lane < 32)
                    ? __hip_atomic_load(flg + lane, __ATOMIC_RELAXED, __HIP_MEMORY_SCOPE_AGENT)
                    : need;
                unsigned long long mset = __ballot(v >= need);
                if ((mset & 0xFFFFFFFFull) == 0xFFFFFFFFull) break;
                __builtin_amdgcn_s_sleep(2);
                if (++it > (1 << 22)) break;     // safety valve
            }
        }
        __syncthreads();
    }
}

__global__ __launch_bounds__(256) void cat_kernel(const float* hf, const float* hb, float* cat) {
    int i = blockIdx.x * 256 + threadIdx.x;      // over 2048*1024
    int row = i >> 10, h = i & 1023;
    cat[i] = (h < HH) ? hf[(size_t)row * HH + h] : hb[(size_t)row * HH + h - HH];
}

__global__ __launch_bounds__(256) void dur3_kernel(const float* __restrict__ h2,
                                                   const float* __restrict__ w,
                                                   const float* __restrict__ b, float* out) {
    int row = blockIdx.x * 256 + threadIdx.x;    // 2048
    float acc = b[0];
    const float* hp = h2 + (size_t)row * 256;
    for (int k = 0; k < 256; k++) acc += hp[k] * w[k];
    out[row] = acc;
}

// durations -> cumsum -> searchsorted index per mel position (-1 = pad)
__global__ __launch_bounds__(256) void length_reg_kernel(const float* __restrict__ dur, int* kidx) {
    int b = blockIdx.x;
    int t = threadIdx.x;
    __shared__ int cum[256];
    cum[t] = (int)rintf(dur[b * TT + t]);
    __syncthreads();
    for (int off = 1; off < 256; off <<= 1) {
        int val = (t >= off) ? cum[t - off] : 0;
        __syncthreads();
        cum[t] += val;
        __syncthreads();
    }
    int total = cum[255];
    for (int pos = t; pos < TM; pos += 256) {
        int lo = 0, hi = 256;
        while (lo < hi) {
            int mid = (lo + hi) >> 1;
            if (cum[mid] <= pos) lo = mid + 1; else hi = mid;
        }
        int idx = (pos < total) ? ((lo < 255) ? lo : 255) : -1;
        kidx[b * TM + pos] = idx;
    }
}

__global__ __launch_bounds__(256) void expand_kernel(const float* __restrict__ enc,
                                                     const int* __restrict__ kidx, float* exp_) {
    int i = blockIdx.x * 256 + threadIdx.x;      // over 8192*512
    int row = i >> 9, h = i & 511;               // row = b*1024 + pos
    int b = row >> 10;
    int id = kidx[row];
    exp_[i] = (id >= 0) ? enc[(size_t)(b * TT + id) * HH + h] : 0.f;
}

__global__ __launch_bounds__(256) void melin_kernel(const float* __restrict__ mel, float* mel_in) {
    int i = blockIdx.x * 256 + threadIdx.x;      // over 8192*80
    if (i >= BB * TM * MELC) return;
    int row = i / MELC, cc = i - row * MELC;
    int b = row >> 10, tpos = row & 1023;
    mel_in[i] = (tpos == 0) ? 0.f : mel[(size_t)(b * TM + tpos - 1) * MELC + cc];
}

// Flash-style MHA: one q-row per thread; K/V tiles (32x64) in LDS.
__global__ __launch_bounds__(256) void attn_kernel(const float* __restrict__ q,
                                                   const float* __restrict__ k,
                                                   const float* __restrict__ v,
                                                   const int* __restrict__ kidx,
                                                   float* __restrict__ ctx) {
    const int bh = blockIdx.y;
    const int b = bh >> 3, h = bh & 7;
    const int qrow = blockIdx.x * 256 + threadIdx.x;
    __shared__ float Ks[32][64];
    __shared__ float Vs[32][64];
    __shared__ float spad[32];

    float qr[64], acc[64];
    const float* qp = q + (size_t)(b * TM + qrow) * HH + h * 64;
#pragma unroll
    for (int d = 0; d < 64; d++) qr[d] = qp[d] * 0.125f;
#pragma unroll
    for (int d = 0; d < 64; d++) acc[d] = 0.f;
    float m = -1e30f, l = 0.f;

    for (int k0 = 0; k0 < TM; k0 += 32) {
        __syncthreads();
#pragma unroll
        for (int i = 0; i < 8; i++) {
            int idx = threadIdx.x + i * 256;     // 0..2047
            int r = idx >> 6, d = idx & 63;
            size_t off = (size_t)(b * TM + k0 + r) * HH + h * 64 + d;
            Ks[r][d] = k[off];
            Vs[r][d] = v[off];
        }
        if (threadIdx.x < 32)
            spad[threadIdx.x] = (kidx[b * TM + k0 + threadIdx.x] < 0) ? 1.f : 0.f;
        __syncthreads();
        for (int r = 0; r < 32; r++) {
            float s = 0.f;
#pragma unroll
            for (int d = 0; d < 64; d++) s += qr[d] * Ks[r][d];
            if (spad[r] != 0.f) s = -1e9f;
            float mn = fmaxf(m, s);
            float corr = __expf(m - mn);
            float p = __expf(s - mn);
            l = l * corr + p;
#pragma unroll
            for (int d = 0; d < 64; d++) acc[d] = acc[d] * corr + p * Vs[r][d];
            m = mn;
        }
    }
    float inv = 1.f / l;
    float* op = ctx + (size_t)(b * TM + qrow) * HH + h * 64;
#pragma unroll
    for (int d = 0; d < 64; d++) op[d] = acc[d] * inv;
}

__global__ __launch_bounds__(256) void decin_kernel(const float* q_in, const float* att, float* dec_in) {
    int i = blockIdx.x * 256 + threadIdx.x;      // over 8192*1024
    int row = i >> 10, h = i & 1023;
    dec_in[i] = (h < HH) ? q_in[(size_t)row * HH + h] : att[(size_t)row * HH + h - HH];
}

__global__ __launch_bounds__(256) void finalize_kernel(const float* melf, const float* logdur, float* out) {
    int i = blockIdx.x * 256 + threadIdx.x;
    if (i < BB * TM * MELC) out[i] = melf[i];
    else if (i < BB * TM * MELC + BB * TT) out[i] = logdur[i - BB * TM * MELC];
}

// ---------------------------------------------------------------------------
extern "C" void kernel_launch(void* const* d_in, const int* in_sizes, int n_in,
                              void* d_out, int out_size, void* d_ws, size_t ws_size,
                              hipStream_t stream) {
    const int*   ph      = (const int*)d_in[0];
    const float* mel     = (const float*)d_in[1];
    const float* durs    = (const float*)d_in[2];
    const float* emb     = (const float*)d_in[3];
    const float* w_ih_f  = (const float*)d_in[4];
    const float* w_hh_f  = (const float*)d_in[5];
    const float* b_ih_f  = (const float*)d_in[6];
    const float* b_hh_f  = (const float*)d_in[7];
    const float* w_ih_b  = (const float*)d_in[8];
    const float* w_hh_b  = (const float*)d_in[9];
    const float* b_ih_b  = (const float*)d_in[10];
    const float* b_hh_b  = (const float*)d_in[11];
    const float* proj_w  = (const float*)d_in[12];
    const float* proj_b  = (const float*)d_in[13];
    const float* dur_w1  = (const float*)d_in[14];
    const float* dur_b1  = (const float*)d_in[15];
    const float* dur_w2  = (const float*)d_in[16];
    const float* dur_b2  = (const float*)d_in[17];
    const float* dur_w3  = (const float*)d_in[18];
    const float* dur_b3  = (const float*)d_in[19];
    const float* melin_w = (const float*)d_in[20];
    const float* melin_b = (const float*)d_in[21];
    const float* attin_w = (const float*)d_in[22];
    const float* attin_b = (const float*)d_in[23];
    const float* atout_w = (const float*)d_in[24];
    const float* atout_b = (const float*)d_in[25];
    const float* dec_wih = (const float*)d_in[26];
    const float* dec_whh = (const float*)d_in[27];
    const float* dec_bih = (const float*)d_in[28];
    const float* dec_bhh = (const float*)d_in[29];
    const float* melo_w  = (const float*)d_in[30];
    const float* melo_b  = (const float*)d_in[31];

    float* ws = (float*)d_ws;
    int*   kidx = (int*)(ws + O_KIDX);
    int*   cnts = (int*)(ws + O_CNT);

    dim3 b256(256);
    auto gemm = [&](const float* A, const float* W, const float* bias, float* C,
                    int M, int N, int K, int act) {
        dim3 g((N + 127) / 128, (M + 127) / 128);
        if (act) gemm_bt<1><<<g, b256, 0, stream>>>(A, W, bias, C, M, N, K);
        else     gemm_bt<0><<<g, b256, 0, stream>>>(A, W, bias, C, M, N, K);
    };

    // 0) zero scan h-buffers + flags (ws is poisoned each call)
    zero_kernel<<<100, b256, 0, stream>>>(ws, 25600);

    // 1) embedding -> x [2048,512]
    embed_kernel<<<(2048 * 512) / 256, b256, 0, stream>>>(ph, emb, ws + O_X);

    // 2) encoder xg = x@W_ih^T + b_ih  [2048,2048] per dir
    gemm(ws + O_X, w_ih_f, b_ih_f, ws + O_XGF, 2048, G4, HH, 0);
    gemm(ws + O_X, w_ih_b, b_ih_b, ws + O_XGB, 2048, G4, HH, 0);

    // 3) encoder scans: fwd+bwd in ONE persistent launch (64 wgs, 2 groups)
    lstm_scan<<<64, b256, 0, stream>>>(ws + O_XGF, ws + O_XGB,
                                       w_hh_f, w_hh_b, b_hh_f, b_hh_b,
                                       ws + O_ENCH, ws + O_HF, ws + O_HB,
                                       cnts, TT, 2);

    // 4) proj([hf,hb]) -> enc [2048,512]
    cat_kernel<<<(2048 * 1024) / 256, b256, 0, stream>>>(ws + O_HF, ws + O_HB, ws + O_CAT);
    gemm(ws + O_CAT, proj_w, proj_b, ws + O_ENC, 2048, HH, 2 * HH, 0);

    // 5) duration predictor
    gemm(ws + O_ENC, dur_w1, dur_b1, ws + O_H1, 2048, HH, HH, 1);
    gemm(ws + O_H1, dur_w2, dur_b2, ws + O_H2, 2048, 256, HH, 1);
    dur3_kernel<<<8, b256, 0, stream>>>(ws + O_H2, dur_w3, dur_b3, ws + O_LOGDUR);

    // 6) length regulation
    length_reg_kernel<<<8, b256, 0, stream>>>(durs, kidx);
    expand_kernel<<<(8192 * 512) / 256, b256, 0, stream>>>(ws + O_ENC, kidx, ws + O_EXP);

    // 7) q_in = Linear(mel shifted) [8192,512]
    melin_kernel<<<(8192 * MELC + 255) / 256, b256, 0, stream>>>(mel, ws + O_MELIN);
    gemm(ws + O_MELIN, melin_w, melin_b, ws + O_QIN, 8192, HH, MELC, 0);

    // 8) q,k,v projections (attn_in_w rows: [wq;wk;wv])
    gemm(ws + O_QIN, attin_w,              attin_b,        ws + O_Q, 8192, HH, HH, 0);
    gemm(ws + O_EXP, attin_w + 512 * 512,  attin_b + 512,  ws + O_K, 8192, HH, HH, 0);
    gemm(ws + O_EXP, attin_w + 1024 * 512, attin_b + 1024, ws + O_V, 8192, HH, HH, 0);

    // 9) attention -> ctx; out projection -> attended
    attn_kernel<<<dim3(4, 64), b256, 0, stream>>>(ws + O_Q, ws + O_K, ws + O_V, kidx, ws + O_CTX);
    gemm(ws + O_CTX, atout_w, atout_b, ws + O_ATT, 8192, HH, HH, 0);

    // 10) decoder: dec_in = [q_in, attended]; xg = dec_in@W_ih^T + b_ih
    decin_kernel<<<(8192 * 1024) / 256, b256, 0, stream>>>(ws + O_QIN, ws + O_ATT, ws + O_DECIN);
    gemm(ws + O_DECIN, dec_wih, dec_bih, ws + O_XGD, 8192, G4, 2 * HH, 0);

    // 11) decoder scan: ONE persistent launch (32 wgs)
    lstm_scan<<<32, b256, 0, stream>>>(ws + O_XGD, ws + O_XGD,
                                       dec_whh, dec_whh, dec_bhh, dec_bhh,
                                       ws + O_DECH, ws + O_HDEC, ws + O_HDEC,
                                       cnts + 64, TM, 1);

    // 12) mel projection + pack outputs
    gemm(ws + O_HDEC, melo_w, melo_b, ws + O_MELF, 8192, MELC, HH, 0);
    finalize_kernel<<<(BB * TM * MELC + BB * TT + 255) / 256, b256, 0, stream>>>(
        ws + O_MELF, ws + O_LOGDUR, (float*)d_out);
}

// Round 5
// 26985.681 us; speedup vs baseline: 1.9427x; 1.0064x over previous
//
#include <hip/hip_runtime.h>

// ---------------------------------------------------------------------------
// KokoroModel: emb -> biLSTM enc -> proj -> dur MLP -> length-regulate ->
//              MHA (teacher-forced) -> dec LSTM -> mel proj
// B=8, T_TEXT=256, T_MEL=1024, H=512, MEL=80, NH=8, HD=64 — all fp32.
// Round 5: same persistent fence-free LSTM scans as round 4, but the
// cross-wg barrier is restructured: per-wg flags spread 256 B apart, ONE
// master wg polls them and publishes a single step counter; all other wgs
// poll that one line. (Round 4's 96wg x 32-flag poll storm saturated the
// coherence point: 19 us/step, 141 MB phantom FETCH.)
// ---------------------------------------------------------------------------

typedef unsigned short u16;
typedef unsigned int u32;

#define BB 8
#define TT 256
#define TM 1024
#define HH 512
#define MELC 80
#define G4 2048   // 4*H

__device__ __forceinline__ float sigmoidf_(float x) { return 1.f / (1.f + __expf(-x)); }

// ------------------------- workspace layout (floats) -----------------------
// O_ENCH: enc h ping-pong [2 groups][2 slots][8][512] = 16384
// O_DECH: dec h ping-pong [2 slots][8][512] = 8192
// O_CNT : sync, 3 groups x 4096 ints: flags at wgi*64, pub at +2048
#define O_ENCH    0u
#define O_DECH    16384u
#define O_CNT     24576u            /* ints, 3*4096 = 12288 (ends at 36864) */
#define O_LOGDUR  36864u
#define O_KIDX    38912u            /* 8192 ints */
#define O_ENC     47104u            /* 2048x512 */
#define O_R1      1095680u          /* 4M: hf|hb|cat  -> exp -> ctx */
#define O_ATT     5289984u          /* 4M attended */
#define O_QIN     9484288u          /* 4M q_in */
#define O_BIG2    13678592u         /* 8M: q|k -> dec_in -> h_dec|mel_f */
#define O_BIG1    22067200u         /* 16.8M: xg_f|xg_b|x -> h1|h2|v|mel_in -> xg_dec */
// sub-offsets
#define O_HF      (O_R1)
#define O_HB      (O_R1 + 1048576u)
#define O_CAT     (O_R1 + 2097152u)
#define O_EXP     (O_R1)
#define O_CTX     (O_R1)
#define O_Q       (O_BIG2)
#define O_K       (O_BIG2 + 4194304u)
#define O_DECIN   (O_BIG2)
#define O_HDEC    (O_BIG2)
#define O_MELF    (O_BIG2 + 4194304u)
#define O_XGF     (O_BIG1)
#define O_XGB     (O_BIG1 + 4194304u)
#define O_X       (O_BIG1 + 8388608u)
#define O_H1      (O_BIG1 + 8388608u)
#define O_H2      (O_BIG1 + 9437184u)
#define O_V       (O_BIG1 + 10485760u)
#define O_MELIN   (O_BIG1 + 14680064u)
#define O_XGD     (O_BIG1)

// ---------------------------------------------------------------------------
__global__ __launch_bounds__(256) void zero_kernel(float* p, int n) {
    int i = blockIdx.x * 256 + threadIdx.x;
    if (i < n) p[i] = 0.f;
}

__global__ __launch_bounds__(256) void embed_kernel(const int* idx, const float* emb, float* x) {
    int i = blockIdx.x * 256 + threadIdx.x;      // over 2048*512
    int tok = i >> 9, h = i & 511;
    x[i] = emb[(size_t)idx[tok] * HH + h];
}

// C[M,N] = act(A[M,K] @ W[N,K]^T + bias[N]);  all fp32.
// 128x128 tile, BK=16, 256 threads, 8x8 micro-tile in 2x2 float4 fragments.
template <int ACT>
__global__ __launch_bounds__(256) void gemm_bt(const float* __restrict__ A,
                                               const float* __restrict__ W,
                                               const float* __restrict__ bias,
                                               float* __restrict__ C,
                                               int M, int N, int K) {
    __shared__ float As[16][132];
    __shared__ float Ws[16][132];
    const int bm = blockIdx.y * 128, bn = blockIdx.x * 128;
    const int tid = threadIdx.x;
    const int tx = tid & 15, ty = tid >> 4;
    float acc[64];
#pragma unroll
    for (int i = 0; i < 64; i++) acc[i] = 0.f;

    for (int k0 = 0; k0 < K; k0 += 16) {
#pragma unroll
        for (int q = 0; q < 2; q++) {
            int fid = tid * 2 + q;               // 0..511
            int m = fid >> 2, kq = (fid & 3) << 2;
            float4 va = *(const float4*)(A + (size_t)(bm + m) * K + k0 + kq);
            As[kq + 0][m] = va.x; As[kq + 1][m] = va.y;
            As[kq + 2][m] = va.z; As[kq + 3][m] = va.w;
            float4 vw = make_float4(0.f, 0.f, 0.f, 0.f);
            if (bn + m < N) vw = *(const float4*)(W + (size_t)(bn + m) * K + k0 + kq);
            Ws[kq + 0][m] = vw.x; Ws[kq + 1][m] = vw.y;
            Ws[kq + 2][m] = vw.z; Ws[kq + 3][m] = vw.w;
        }
        __syncthreads();
#pragma unroll
        for (int kk = 0; kk < 16; kk++) {
            float4 a0 = *(const float4*)&As[kk][ty * 4];
            float4 a1 = *(const float4*)&As[kk][64 + ty * 4];
            float4 b0 = *(const float4*)&Ws[kk][tx * 4];
            float4 b1 = *(const float4*)&Ws[kk][64 + tx * 4];
            float av[8] = {a0.x, a0.y, a0.z, a0.w, a1.x, a1.y, a1.z, a1.w};
            float bv[8] = {b0.x, b0.y, b0.z, b0.w, b1.x, b1.y, b1.z, b1.w};
#pragma unroll
            for (int ih = 0; ih < 2; ih++)
#pragma unroll
                for (int ii = 0; ii < 4; ii++) {
                    float a = av[ih * 4 + ii];
#pragma unroll
                    for (int jh = 0; jh < 2; jh++)
#pragma unroll
                        for (int jjv = 0; jjv < 4; jjv++)
                            acc[(ih * 2 + jh) * 16 + ii * 4 + jjv] =
                                fmaf(a, bv[jh * 4 + jjv], acc[(ih * 2 + jh) * 16 + ii * 4 + jjv]);
                }
        }
        __syncthreads();
    }
#pragma unroll
    for (int ih = 0; ih < 2; ih++)
#pragma unroll
        for (int jh = 0; jh < 2; jh++) {
            int n = bn + jh * 64 + tx * 4;
            if (n >= N) continue;
            float4 bb = make_float4(0.f, 0.f, 0.f, 0.f);
            if (bias) bb = *(const float4*)(bias + n);
#pragma unroll
            for (int ii = 0; ii < 4; ii++) {
                int m = bm + ih * 64 + ty * 4 + ii;
                float4 o;
                o.x = acc[(ih * 2 + jh) * 16 + ii * 4 + 0] + bb.x;
                o.y = acc[(ih * 2 + jh) * 16 + ii * 4 + 1] + bb.y;
                o.z = acc[(ih * 2 + jh) * 16 + ii * 4 + 2] + bb.z;
                o.w = acc[(ih * 2 + jh) * 16 + ii * 4 + 3] + bb.w;
                if (ACT == 1) {
                    o.x = fmaxf(o.x, 0.f); o.y = fmaxf(o.y, 0.f);
                    o.z = fmaxf(o.z, 0.f); o.w = fmaxf(o.w, 0.f);
                }
                *(float4*)(C + (size_t)m * N + n) = o;
            }
        }
}

// ---------------------------------------------------------------------------
// Persistent fence-free LSTM scan (layout as round 4: 32 wgs/group, wg owns
// 16 j x 4 gates x all 8 batches; W_hh in VGPRs; sc1 h exchange).
// Barrier v2: wg stores flag[wgi*64]=t+1 (after vmcnt0); master wg polls the
// 32 spread flags and publishes pub=t+1; others poll only pub.
__global__ __launch_bounds__(256, 1) void lstm_scan(
    const float* __restrict__ xg0, const float* __restrict__ xg1,
    const float* __restrict__ whh0, const float* __restrict__ whh1,
    const float* __restrict__ bhh0, const float* __restrict__ bhh1,
    float* hbuf, float* hout0, float* hout1,
    int* sync, int T, int ndir) {
    const int wg = blockIdx.x;
    const int group = wg >> 5;                   // dir (or 0)
    const int wgi = wg & 31;
    const int dir = (ndir == 2) ? group : 0;
    const float* xg  = dir ? xg1 : xg0;
    const float* whh = dir ? whh1 : whh0;
    const float* bhh = dir ? bhh1 : bhh0;
    float* hout = dir ? hout1 : hout0;
    float* hb = hbuf + group * 8192;             // [2 slots][8][512]
    int* syn = sync + group * 4096;              // flags wgi*64, pub +2048

    const int wave = threadIdx.x >> 6;
    const int lane = threadIdx.x & 63;
    const int gate = lane & 3;
    const int ks = lane >> 2;                    // k-slice of 32
    const int jq = wgi * 16 + wave * 4;

    // weights: wv[jj][i4] = W_hh[gate*512 + jq+jj][ks*32 + i4*4 ..+4)
    float4 wv[4][8];
#pragma unroll
    for (int jj = 0; jj < 4; jj++) {
        const float4* wp = (const float4*)(whh + (size_t)(gate * HH + jq + jj) * HH + ks * 32);
#pragma unroll
        for (int i = 0; i < 8; i++) wv[jj][i] = wp[i];
    }
    float xb0 = bhh[gate * HH + jq + 0];
    float xb1 = bhh[gate * HH + jq + 1];
    float xb2 = bhh[gate * HH + jq + 2];
    float xb3 = bhh[gate * HH + jq + 3];
    float cst[32];                               // c[b][jj], replicated all lanes
#pragma unroll
    for (int i = 0; i < 32; i++) cst[i] = 0.f;

    __shared__ float hs[4096];                   // staged h, bank-rotated

    for (int t = 0; t < T; t++) {
        const int te = dir ? (T - 1 - t) : t;
        // prefetch xg rows (only ks==0 lanes consume)
        float4 xgv[8];
        if (ks == 0) {
#pragma unroll
            for (int b = 0; b < 8; b++)
                xgv[b] = *(const float4*)(xg + (size_t)(b * T + te) * G4 + gate * HH + jq);
        }
        // stage h_prev from global (sc1) into LDS with bank rotation:
        // logical [b][k] -> lds[b*512 + (k&~31) + ((k + (k>>5)*4) & 31)]
        const float* hg = hb + ((t + 1) & 1) * 4096;
#pragma unroll
        for (int n = 0; n < 16; n++) {
            int idx = threadIdx.x + n * 256;
            int kk = idx & 511;
            float v = __hip_atomic_load(hg + idx, __ATOMIC_RELAXED, __HIP_MEMORY_SCOPE_AGENT);
            hs[(idx & ~511) + (kk & ~31) + (((kk & 31) + ((kk >> 5) << 2)) & 31)] = v;
        }
        __syncthreads();

        float hw_mine = 0.f;
#pragma unroll
        for (int b = 0; b < 8; b++) {
            float a0, a1, a2, a3;
            if (ks == 0) {
                a0 = xgv[b].x + xb0; a1 = xgv[b].y + xb1;
                a2 = xgv[b].z + xb2; a3 = xgv[b].w + xb3;
            } else { a0 = a1 = a2 = a3 = 0.f; }
#pragma unroll
            for (int i4 = 0; i4 < 8; i4++) {
                const float4 h4 = *(const float4*)
                    &hs[b * HH + ks * 32 + (((i4 + ks) & 7) << 2)];
                a0 = fmaf(wv[0][i4].x, h4.x, a0); a0 = fmaf(wv[0][i4].y, h4.y, a0);
                a0 = fmaf(wv[0][i4].z, h4.z, a0); a0 = fmaf(wv[0][i4].w, h4.w, a0);
                a1 = fmaf(wv[1][i4].x, h4.x, a1); a1 = fmaf(wv[1][i4].y, h4.y, a1);
                a1 = fmaf(wv[1][i4].z, h4.z, a1); a1 = fmaf(wv[1][i4].w, h4.w, a1);
                a2 = fmaf(wv[2][i4].x, h4.x, a2); a2 = fmaf(wv[2][i4].y, h4.y, a2);
                a2 = fmaf(wv[2][i4].z, h4.z, a2); a2 = fmaf(wv[2][i4].w, h4.w, a2);
                a3 = fmaf(wv[3][i4].x, h4.x, a3); a3 = fmaf(wv[3][i4].y, h4.y, a3);
                a3 = fmaf(wv[3][i4].z, h4.z, a3); a3 = fmaf(wv[3][i4].w, h4.w, a3);
            }
            // reduce over ks (lane bits 5:2)
            a0 += __shfl_xor(a0, 4);  a1 += __shfl_xor(a1, 4);
            a2 += __shfl_xor(a2, 4);  a3 += __shfl_xor(a3, 4);
            a0 += __shfl_xor(a0, 8);  a1 += __shfl_xor(a1, 8);
            a2 += __shfl_xor(a2, 8);  a3 += __shfl_xor(a3, 8);
            a0 += __shfl_xor(a0, 16); a1 += __shfl_xor(a1, 16);
            a2 += __shfl_xor(a2, 16); a3 += __shfl_xor(a3, 16);
            a0 += __shfl_xor(a0, 32); a1 += __shfl_xor(a1, 32);
            a2 += __shfl_xor(a2, 32); a3 += __shfl_xor(a3, 32);
            // gather 4 gates per jj; every lane computes all (b,jj)
            const int base = lane & ~3;
#pragma unroll
            for (int jj = 0; jj < 4; jj++) {
                float a = (jj == 0) ? a0 : (jj == 1) ? a1 : (jj == 2) ? a2 : a3;
                float gi = __shfl(a, base + 0);
                float gf = __shfl(a, base + 1);
                float gg = __shfl(a, base + 2);
                float go = __shfl(a, base + 3);
                float i_ = sigmoidf_(gi), f_ = sigmoidf_(gf);
                float G_ = tanhf(gg),     o_ = sigmoidf_(go);
                float cn = f_ * cst[b * 4 + jj] + i_ * G_;
                cst[b * 4 + jj] = cn;
                float hn = o_ * tanhf(cn);
                if (lane == b * 4 + jj) hw_mine = hn;
            }
        }
        // write h (sc1) + hout (normal); lanes 0..31: (b=lane>>2, jj=lane&3)
        if (lane < 32) {
            int b = lane >> 2, jj = lane & 3, j = jq + jj;
            __hip_atomic_store(hb + (t & 1) * 4096 + b * HH + j, hw_mine,
                               __ATOMIC_RELAXED, __HIP_MEMORY_SCOPE_AGENT);
            hout[(size_t)(b * T + te) * HH + j] = hw_mine;
        }
        __builtin_amdgcn_s_waitcnt(0);           // h stores acked at coherence pt
        __syncthreads();                         // all 4 waves' stores done
        const int need = t + 1;
        if (threadIdx.x == 0)
            __hip_atomic_store(syn + wgi * 64, need, __ATOMIC_RELAXED, __HIP_MEMORY_SCOPE_AGENT);
        if (wgi == 0) {
            // master: wave 0 polls the 32 spread flags, then publishes pub
            if (wave == 0) {
                int it = 0;
                while (true) {
                    int v = (lane < 32)
                        ? __hip_atomic_load(syn + lane * 64, __ATOMIC_RELAXED, __HIP_MEMORY_SCOPE_AGENT)
                        : need;
                    unsigned long long mset = __ballot(v >= need);
                    if ((mset & 0xFFFFFFFFull) == 0xFFFFFFFFull) break;
                    __builtin_amdgcn_s_sleep(2);
                    if (++it > (1 << 24)) break; // safety valve
                }
                if (lane == 0)
                    __hip_atomic_store(syn + 2048, need, __ATOMIC_RELAXED, __HIP_MEMORY_SCOPE_AGENT);
            }
        } else {
            // others: one lane polls the single published step
            if (threadIdx.x == 0) {
                int it = 0;
                while (__hip_atomic_load(syn + 2048, __ATOMIC_RELAXED, __HIP_MEMORY_SCOPE_AGENT) < need) {
                    __builtin_amdgcn_s_sleep(4);
                    if (++it > (1 << 24)) break; // safety valve
                }
            }
        }
        __syncthreads();
    }
}

__global__ __launch_bounds__(256) void cat_kernel(const float* hf, const float* hb, float* cat) {
    int i = blockIdx.x * 256 + threadIdx.x;      // over 2048*1024
    int row = i >> 10, h = i & 1023;
    cat[i] = (h < HH) ? hf[(size_t)row * HH + h] : hb[(size_t)row * HH + h - HH];
}

__global__ __launch_bounds__(256) void dur3_kernel(const float* __restrict__ h2,
                                                   const float* __restrict__ w,
                                                   const float* __restrict__ b, float* out) {
    int row = blockIdx.x * 256 + threadIdx.x;    // 2048
    float acc = b[0];
    const float* hp = h2 + (size_t)row * 256;
    for (int k = 0; k < 256; k++) acc += hp[k] * w[k];
    out[row] = acc;
}

// durations -> cumsum -> searchsorted index per mel position (-1 = pad)
__global__ __launch_bounds__(256) void length_reg_kernel(const float* __restrict__ dur, int* kidx) {
    int b = blockIdx.x;
    int t = threadIdx.x;
    __shared__ int cum[256];
    cum[t] = (int)rintf(dur[b * TT + t]);
    __syncthreads();
    for (int off = 1; off < 256; off <<= 1) {
        int val = (t >= off) ? cum[t - off] : 0;
        __syncthreads();
        cum[t] += val;
        __syncthreads();
    }
    int total = cum[255];
    for (int pos = t; pos < TM; pos += 256) {
        int lo = 0, hi = 256;
        while (lo < hi) {
            int mid = (lo + hi) >> 1;
            if (cum[mid] <= pos) lo = mid + 1; else hi = mid;
        }
        int idx = (pos < total) ? ((lo < 255) ? lo : 255) : -1;
        kidx[b * TM + pos] = idx;
    }
}

__global__ __launch_bounds__(256) void expand_kernel(const float* __restrict__ enc,
                                                     const int* __restrict__ kidx, float* exp_) {
    int i = blockIdx.x * 256 + threadIdx.x;      // over 8192*512
    int row = i >> 9, h = i & 511;               // row = b*1024 + pos
    int b = row >> 10;
    int id = kidx[row];
    exp_[i] = (id >= 0) ? enc[(size_t)(b * TT + id) * HH + h] : 0.f;
}

__global__ __launch_bounds__(256) void melin_kernel(const float* __restrict__ mel, float* mel_in) {
    int i = blockIdx.x * 256 + threadIdx.x;      // over 8192*80
    if (i >= BB * TM * MELC) return;
    int row = i / MELC, cc = i - row * MELC;
    int b = row >> 10, tpos = row & 1023;
    mel_in[i] = (tpos == 0) ? 0.f : mel[(size_t)(b * TM + tpos - 1) * MELC + cc];
}

// Flash-style MHA: one q-row per thread; K/V tiles (32x64) in LDS.
__global__ __launch_bounds__(256) void attn_kernel(const float* __restrict__ q,
                                                   const float* __restrict__ k,
                                                   const float* __restrict__ v,
                                                   const int* __restrict__ kidx,
                                                   float* __restrict__ ctx) {
    const int bh = blockIdx.y;
    const int b = bh >> 3, h = bh & 7;
    const int qrow = blockIdx.x * 256 + threadIdx.x;
    __shared__ float Ks[32][64];
    __shared__ float Vs[32][64];
    __shared__ float spad[32];

    float qr[64], acc[64];
    const float* qp = q + (size_t)(b * TM + qrow) * HH + h * 64;
#pragma unroll
    for (int d = 0; d < 64; d++) qr[d] = qp[d] * 0.125f;
#pragma unroll
    for (int d = 0; d < 64; d++) acc[d] = 0.f;
    float m = -1e30f, l = 0.f;

    for (int k0 = 0; k0 < TM; k0 += 32) {
        __syncthreads();
#pragma unroll
        for (int i = 0; i < 8; i++) {
            int idx = threadIdx.x + i * 256;     // 0..2047
            int r = idx >> 6, d = idx & 63;
            size_t off = (size_t)(b * TM + k0 + r) * HH + h * 64 + d;
            Ks[r][d] = k[off];
            Vs[r][d] = v[off];
        }
        if (threadIdx.x < 32)
            spad[threadIdx.x] = (kidx[b * TM + k0 + threadIdx.x] < 0) ? 1.f : 0.f;
        __syncthreads();
        for (int r = 0; r < 32; r++) {
            float s = 0.f;
#pragma unroll
            for (int d = 0; d < 64; d++) s += qr[d] * Ks[r][d];
            if (spad[r] != 0.f) s = -1e9f;
            float mn = fmaxf(m, s);
            float corr = __expf(m - mn);
            float p = __expf(s - mn);
            l = l * corr + p;
#pragma unroll
            for (int d = 0; d < 64; d++) acc[d] = acc[d] * corr + p * Vs[r][d];
            m = mn;
        }
    }
    float inv = 1.f / l;
    float* op = ctx + (size_t)(b * TM + qrow) * HH + h * 64;
#pragma unroll
    for (int d = 0; d < 64; d++) op[d] = acc[d] * inv;
}

__global__ __launch_bounds__(256) void decin_kernel(const float* q_in, const float* att, float* dec_in) {
    int i = blockIdx.x * 256 + threadIdx.x;      // over 8192*1024
    int row = i >> 10, h = i & 1023;
    dec_in[i] = (h < HH) ? q_in[(size_t)row * HH + h] : att[(size_t)row * HH + h - HH];
}

__global__ __launch_bounds__(256) void finalize_kernel(const float* melf, const float* logdur, float* out) {
    int i = blockIdx.x * 256 + threadIdx.x;
    if (i < BB * TM * MELC) out[i] = melf[i];
    else if (i < BB * TM * MELC + BB * TT) out[i] = logdur[i - BB * TM * MELC];
}

// ---------------------------------------------------------------------------
extern "C" void kernel_launch(void* const* d_in, const int* in_sizes, int n_in,
                              void* d_out, int out_size, void* d_ws, size_t ws_size,
                              hipStream_t stream) {
    const int*   ph      = (const int*)d_in[0];
    const float* mel     = (const float*)d_in[1];
    const float* durs    = (const float*)d_in[2];
    const float* emb     = (const float*)d_in[3];
    const float* w_ih_f  = (const float*)d_in[4];
    const float* w_hh_f  = (const float*)d_in[5];
    const float* b_ih_f  = (const float*)d_in[6];
    const float* b_hh_f  = (const float*)d_in[7];
    const float* w_ih_b  = (const float*)d_in[8];
    const float* w_hh_b  = (const float*)d_in[9];
    const float* b_ih_b  = (const float*)d_in[10];
    const float* b_hh_b  = (const float*)d_in[11];
    const float* proj_w  = (const float*)d_in[12];
    const float* proj_b  = (const float*)d_in[13];
    const float* dur_w1  = (const float*)d_in[14];
    const float* dur_b1  = (const float*)d_in[15];
    const float* dur_w2  = (const float*)d_in[16];
    const float* dur_b2  = (const float*)d_in[17];
    const float* dur_w3  = (const float*)d_in[18];
    const float* dur_b3  = (const float*)d_in[19];
    const float* melin_w = (const float*)d_in[20];
    const float* melin_b = (const float*)d_in[21];
    const float* attin_w = (const float*)d_in[22];
    const float* attin_b = (const float*)d_in[23];
    const float* atout_w = (const float*)d_in[24];
    const float* atout_b = (const float*)d_in[25];
    const float* dec_wih = (const float*)d_in[26];
    const float* dec_whh = (const float*)d_in[27];
    const float* dec_bih = (const float*)d_in[28];
    const float* dec_bhh = (const float*)d_in[29];
    const float* melo_w  = (const float*)d_in[30];
    const float* melo_b  = (const float*)d_in[31];

    float* ws = (float*)d_ws;
    int*   kidx = (int*)(ws + O_KIDX);
    int*   cnts = (int*)(ws + O_CNT);

    dim3 b256(256);
    auto gemm = [&](const float* A, const float* W, const float* bias, float* C,
                    int M, int N, int K, int act) {
        dim3 g((N + 127) / 128, (M + 127) / 128);
        if (act) gemm_bt<1><<<g, b256, 0, stream>>>(A, W, bias, C, M, N, K);
        else     gemm_bt<0><<<g, b256, 0, stream>>>(A, W, bias, C, M, N, K);
    };

    // 0) zero scan h-buffers + sync region (ws is poisoned each call)
    zero_kernel<<<144, b256, 0, stream>>>(ws, 36864);

    // 1) embedding -> x [2048,512]
    embed_kernel<<<(2048 * 512) / 256, b256, 0, stream>>>(ph, emb, ws + O_X);

    // 2) encoder xg = x@W_ih^T + b_ih  [2048,2048] per dir
    gemm(ws + O_X, w_ih_f, b_ih_f, ws + O_XGF, 2048, G4, HH, 0);
    gemm(ws + O_X, w_ih_b, b_ih_b, ws + O_XGB, 2048, G4, HH, 0);

    // 3) encoder scans: fwd+bwd in ONE persistent launch (64 wgs, 2 groups)
    lstm_scan<<<64, b256, 0, stream>>>(ws + O_XGF, ws + O_XGB,
                                       w_hh_f, w_hh_b, b_hh_f, b_hh_b,
                                       ws + O_ENCH, ws + O_HF, ws + O_HB,
                                       cnts, TT, 2);

    // 4) proj([hf,hb]) -> enc [2048,512]
    cat_kernel<<<(2048 * 1024) / 256, b256, 0, stream>>>(ws + O_HF, ws + O_HB, ws + O_CAT);
    gemm(ws + O_CAT, proj_w, proj_b, ws + O_ENC, 2048, HH, 2 * HH, 0);

    // 5) duration predictor
    gemm(ws + O_ENC, dur_w1, dur_b1, ws + O_H1, 2048, HH, HH, 1);
    gemm(ws + O_H1, dur_w2, dur_b2, ws + O_H2, 2048, 256, HH, 1);
    dur3_kernel<<<8, b256, 0, stream>>>(ws + O_H2, dur_w3, dur_b3, ws + O_LOGDUR);

    // 6) length regulation
    length_reg_kernel<<<8, b256, 0, stream>>>(durs, kidx);
    expand_kernel<<<(8192 * 512) / 256, b256, 0, stream>>>(ws + O_ENC, kidx, ws + O_EXP);

    // 7) q_in = Linear(mel shifted) [8192,512]
    melin_kernel<<<(8192 * MELC + 255) / 256, b256, 0, stream>>>(mel, ws + O_MELIN);
    gemm(ws + O_MELIN, melin_w, melin_b, ws + O_QIN, 8192, HH, MELC, 0);

    // 8) q,k,v projections (attn_in_w rows: [wq;wk;wv])
    gemm(ws + O_QIN, attin_w,              attin_b,        ws + O_Q, 8192, HH, HH, 0);
    gemm(ws + O_EXP, attin_w + 512 * 512,  attin_b + 512,  ws + O_K, 8192, HH, HH, 0);
    gemm(ws + O_EXP, attin_w + 1024 * 512, attin_b + 1024, ws + O_V, 8192, HH, HH, 0);

    // 9) attention -> ctx; out projection -> attended
    attn_kernel<<<dim3(4, 64), b256, 0, stream>>>(ws + O_Q, ws + O_K, ws + O_V, kidx, ws + O_CTX);
    gemm(ws + O_CTX, atout_w, atout_b, ws + O_ATT, 8192, HH, HH, 0);

    // 10) decoder: dec_in = [q_in, attended]; xg = dec_in@W_ih^T + b_ih
    decin_kernel<<<(8192 * 1024) / 256, b256, 0, stream>>>(ws + O_QIN, ws + O_ATT, ws + O_DECIN);
    gemm(ws + O_DECIN, dec_wih, dec_bih, ws + O_XGD, 8192, G4, 2 * HH, 0);

    // 11) decoder scan: ONE persistent launch (32 wgs)
    lstm_scan<<<32, b256, 0, stream>>>(ws + O_XGD, ws + O_XGD,
                                       dec_whh, dec_whh, dec_bhh, dec_bhh,
                                       ws + O_DECH, ws + O_HDEC, ws + O_HDEC,
                                       cnts + 8192, TM, 1);

    // 12) mel projection + pack outputs
    gemm(ws + O_HDEC, melo_w, melo_b, ws + O_MELF, 8192, MELC, HH, 0);
    finalize_kernel<<<(BB * TM * MELC + BB * TT + 255) / 256, b256, 0, stream>>>(
        ws + O_MELF, ws + O_LOGDUR, (float*)d_out);
}

// Round 6
// 16875.554 us; speedup vs baseline: 3.1066x; 1.5991x over previous
//
#include <hip/hip_runtime.h>

// ---------------------------------------------------------------------------
// KokoroModel: emb -> biLSTM enc -> proj -> dur MLP -> length-regulate ->
//              MHA (teacher-forced) -> dec LSTM -> mel proj
// B=8, T_TEXT=256, T_MEL=1024, H=512, MEL=80, NH=8, HD=64 — all fp32.
// Round 6: persistent LSTM scan, sc1 h-exchange VECTORIZED (dwordx4 sc0 sc1
// via inline asm — round 4/5's 4096 scalar-dword agent loads per wg per step
// were the real bottleneck, not the barrier). Gate transcendentals owner-
// lane-gated + fast tanh; scalar c per lane.
// ---------------------------------------------------------------------------

typedef unsigned short u16;
typedef unsigned int u32;
typedef float f4 __attribute__((ext_vector_type(4)));

#define BB 8
#define TT 256
#define TM 1024
#define HH 512
#define MELC 80
#define G4 2048   // 4*H

__device__ __forceinline__ float sigmoidf_(float x) { return 1.f / (1.f + __expf(-x)); }
__device__ __forceinline__ float tanh_fast(float x) {
    float e = __expf(2.f * x);
    return 1.f - 2.f / (e + 1.f);
}

// ------------------------- workspace layout (floats) -----------------------
// O_ENCH: enc h ping-pong [2 groups][2 slots][8][512] = 16384
// O_DECH: dec h ping-pong [2 slots][8][512] = 8192
// O_CNT : sync, 3 groups x 4096 ints: flags at wgi*64, pub at +2048
#define O_ENCH    0u
#define O_DECH    16384u
#define O_CNT     24576u            /* ints, 3*4096 = 12288 (ends at 36864) */
#define O_LOGDUR  36864u
#define O_KIDX    38912u            /* 8192 ints */
#define O_ENC     47104u            /* 2048x512 */
#define O_R1      1095680u          /* 4M: hf|hb|cat  -> exp -> ctx */
#define O_ATT     5289984u          /* 4M attended */
#define O_QIN     9484288u          /* 4M q_in */
#define O_BIG2    13678592u         /* 8M: q|k -> dec_in -> h_dec|mel_f */
#define O_BIG1    22067200u         /* 16.8M: xg_f|xg_b|x -> h1|h2|v|mel_in -> xg_dec */
// sub-offsets
#define O_HF      (O_R1)
#define O_HB      (O_R1 + 1048576u)
#define O_CAT     (O_R1 + 2097152u)
#define O_EXP     (O_R1)
#define O_CTX     (O_R1)
#define O_Q       (O_BIG2)
#define O_K       (O_BIG2 + 4194304u)
#define O_DECIN   (O_BIG2)
#define O_HDEC    (O_BIG2)
#define O_MELF    (O_BIG2 + 4194304u)
#define O_XGF     (O_BIG1)
#define O_XGB     (O_BIG1 + 4194304u)
#define O_X       (O_BIG1 + 8388608u)
#define O_H1      (O_BIG1 + 8388608u)
#define O_H2      (O_BIG1 + 9437184u)
#define O_V       (O_BIG1 + 10485760u)
#define O_MELIN   (O_BIG1 + 14680064u)
#define O_XGD     (O_BIG1)

// ---------------------------------------------------------------------------
__global__ __launch_bounds__(256) void zero_kernel(float* p, int n) {
    int i = blockIdx.x * 256 + threadIdx.x;
    if (i < n) p[i] = 0.f;
}

__global__ __launch_bounds__(256) void embed_kernel(const int* idx, const float* emb, float* x) {
    int i = blockIdx.x * 256 + threadIdx.x;      // over 2048*512
    int tok = i >> 9, h = i & 511;
    x[i] = emb[(size_t)idx[tok] * HH + h];
}

// C[M,N] = act(A[M,K] @ W[N,K]^T + bias[N]);  all fp32.
// 128x128 tile, BK=16, 256 threads, 8x8 micro-tile in 2x2 float4 fragments.
template <int ACT>
__global__ __launch_bounds__(256) void gemm_bt(const float* __restrict__ A,
                                               const float* __restrict__ W,
                                               const float* __restrict__ bias,
                                               float* __restrict__ C,
                                               int M, int N, int K) {
    __shared__ float As[16][132];
    __shared__ float Ws[16][132];
    const int bm = blockIdx.y * 128, bn = blockIdx.x * 128;
    const int tid = threadIdx.x;
    const int tx = tid & 15, ty = tid >> 4;
    float acc[64];
#pragma unroll
    for (int i = 0; i < 64; i++) acc[i] = 0.f;

    for (int k0 = 0; k0 < K; k0 += 16) {
#pragma unroll
        for (int q = 0; q < 2; q++) {
            int fid = tid * 2 + q;               // 0..511
            int m = fid >> 2, kq = (fid & 3) << 2;
            float4 va = *(const float4*)(A + (size_t)(bm + m) * K + k0 + kq);
            As[kq + 0][m] = va.x; As[kq + 1][m] = va.y;
            As[kq + 2][m] = va.z; As[kq + 3][m] = va.w;
            float4 vw = make_float4(0.f, 0.f, 0.f, 0.f);
            if (bn + m < N) vw = *(const float4*)(W + (size_t)(bn + m) * K + k0 + kq);
            Ws[kq + 0][m] = vw.x; Ws[kq + 1][m] = vw.y;
            Ws[kq + 2][m] = vw.z; Ws[kq + 3][m] = vw.w;
        }
        __syncthreads();
#pragma unroll
        for (int kk = 0; kk < 16; kk++) {
            float4 a0 = *(const float4*)&As[kk][ty * 4];
            float4 a1 = *(const float4*)&As[kk][64 + ty * 4];
            float4 b0 = *(const float4*)&Ws[kk][tx * 4];
            float4 b1 = *(const float4*)&Ws[kk][64 + tx * 4];
            float av[8] = {a0.x, a0.y, a0.z, a0.w, a1.x, a1.y, a1.z, a1.w};
            float bv[8] = {b0.x, b0.y, b0.z, b0.w, b1.x, b1.y, b1.z, b1.w};
#pragma unroll
            for (int ih = 0; ih < 2; ih++)
#pragma unroll
                for (int ii = 0; ii < 4; ii++) {
                    float a = av[ih * 4 + ii];
#pragma unroll
                    for (int jh = 0; jh < 2; jh++)
#pragma unroll
                        for (int jjv = 0; jjv < 4; jjv++)
                            acc[(ih * 2 + jh) * 16 + ii * 4 + jjv] =
                                fmaf(a, bv[jh * 4 + jjv], acc[(ih * 2 + jh) * 16 + ii * 4 + jjv]);
                }
        }
        __syncthreads();
    }
#pragma unroll
    for (int ih = 0; ih < 2; ih++)
#pragma unroll
        for (int jh = 0; jh < 2; jh++) {
            int n = bn + jh * 64 + tx * 4;
            if (n >= N) continue;
            float4 bb = make_float4(0.f, 0.f, 0.f, 0.f);
            if (bias) bb = *(const float4*)(bias + n);
#pragma unroll
            for (int ii = 0; ii < 4; ii++) {
                int m = bm + ih * 64 + ty * 4 + ii;
                float4 o;
                o.x = acc[(ih * 2 + jh) * 16 + ii * 4 + 0] + bb.x;
                o.y = acc[(ih * 2 + jh) * 16 + ii * 4 + 1] + bb.y;
                o.z = acc[(ih * 2 + jh) * 16 + ii * 4 + 2] + bb.z;
                o.w = acc[(ih * 2 + jh) * 16 + ii * 4 + 3] + bb.w;
                if (ACT == 1) {
                    o.x = fmaxf(o.x, 0.f); o.y = fmaxf(o.y, 0.f);
                    o.z = fmaxf(o.z, 0.f); o.w = fmaxf(o.w, 0.f);
                }
                *(float4*)(C + (size_t)m * N + n) = o;
            }
        }
}

// ---------------------------------------------------------------------------
// Persistent fence-free LSTM scan. 32 wgs/group; wg owns 16 j x 4 gates x all
// 8 batches; W_hh in VGPRs. h exchange: producers store sc1 dwords; consumers
// stage 16KB/step via dwordx4 sc0 sc1 (inline asm) -> LDS (bank-rotated).
// Barrier: per-wg spread flags -> master wg -> single pub word.
__global__ __launch_bounds__(256, 1) void lstm_scan(
    const float* __restrict__ xg0, const float* __restrict__ xg1,
    const float* __restrict__ whh0, const float* __restrict__ whh1,
    const float* __restrict__ bhh0, const float* __restrict__ bhh1,
    float* hbuf, float* hout0, float* hout1,
    int* sync, int T, int ndir) {
    const int wg = blockIdx.x;
    const int group = wg >> 5;                   // dir (or 0)
    const int wgi = wg & 31;
    const int dir = (ndir == 2) ? group : 0;
    const float* xg  = dir ? xg1 : xg0;
    const float* whh = dir ? whh1 : whh0;
    const float* bhh = dir ? bhh1 : bhh0;
    float* hout = dir ? hout1 : hout0;
    float* hb = hbuf + group * 8192;             // [2 slots][8][512]
    int* syn = sync + group * 4096;              // flags wgi*64, pub +2048

    const int wave = threadIdx.x >> 6;
    const int lane = threadIdx.x & 63;
    const int gate = lane & 3;
    const int ks = lane >> 2;                    // k-slice of 32
    const int jq = wgi * 16 + wave * 4;

    // weights: wv[jj][i4] = W_hh[gate*512 + jq+jj][ks*32 + i4*4 ..+4)
    float4 wv[4][8];
#pragma unroll
    for (int jj = 0; jj < 4; jj++) {
        const float4* wp = (const float4*)(whh + (size_t)(gate * HH + jq + jj) * HH + ks * 32);
#pragma unroll
        for (int i = 0; i < 8; i++) wv[jj][i] = wp[i];
    }
    float xb0 = bhh[gate * HH + jq + 0];
    float xb1 = bhh[gate * HH + jq + 1];
    float xb2 = bhh[gate * HH + jq + 2];
    float xb3 = bhh[gate * HH + jq + 3];
    float c_ = 0.f;                              // owner-lane cell state

    __shared__ float hs[4096];                   // staged h, bank-rotated

    for (int t = 0; t < T; t++) {
        const int te = dir ? (T - 1 - t) : t;
        // prefetch xg rows (normal cached loads; only ks==0 lanes consume)
        float4 xgv[8];
        if (ks == 0) {
#pragma unroll
            for (int b = 0; b < 8; b++)
                xgv[b] = *(const float4*)(xg + (size_t)(b * T + te) * G4 + gate * HH + jq);
        }
        // stage h_prev: 4 x dwordx4 sc0 sc1 per thread (coherence-point reads,
        // 16B granularity), then bank-rotated LDS writes.
        const float* hg = hb + ((t + 1) & 1) * 4096;
        f4 hv[4];
#pragma unroll
        for (int q = 0; q < 4; q++) {
            const float* ap = hg + ((q * 256 + threadIdx.x) << 2);
            asm volatile("global_load_dwordx4 %0, %1, off sc0 sc1"
                         : "=v"(hv[q]) : "v"(ap) : "memory");
        }
        __builtin_amdgcn_s_waitcnt(0);
#pragma unroll
        for (int q = 0; q < 4; q++) {
            int flat = (q * 256 + threadIdx.x) << 2;
            int bb = flat >> 9, kk = flat & 511;
            int blk = kk >> 5, off = kk & 31;
            *(f4*)&hs[bb * HH + blk * 32 + ((off + (blk << 2)) & 31)] = hv[q];
        }
        __syncthreads();

        float hw_mine = 0.f;
#pragma unroll
        for (int b = 0; b < 8; b++) {
            float a0, a1, a2, a3;
            if (ks == 0) {
                a0 = xgv[b].x + xb0; a1 = xgv[b].y + xb1;
                a2 = xgv[b].z + xb2; a3 = xgv[b].w + xb3;
            } else { a0 = a1 = a2 = a3 = 0.f; }
#pragma unroll
            for (int i4 = 0; i4 < 8; i4++) {
                const float4 h4 = *(const float4*)
                    &hs[b * HH + ks * 32 + (((i4 + ks) & 7) << 2)];
                a0 = fmaf(wv[0][i4].x, h4.x, a0); a0 = fmaf(wv[0][i4].y, h4.y, a0);
                a0 = fmaf(wv[0][i4].z, h4.z, a0); a0 = fmaf(wv[0][i4].w, h4.w, a0);
                a1 = fmaf(wv[1][i4].x, h4.x, a1); a1 = fmaf(wv[1][i4].y, h4.y, a1);
                a1 = fmaf(wv[1][i4].z, h4.z, a1); a1 = fmaf(wv[1][i4].w, h4.w, a1);
                a2 = fmaf(wv[2][i4].x, h4.x, a2); a2 = fmaf(wv[2][i4].y, h4.y, a2);
                a2 = fmaf(wv[2][i4].z, h4.z, a2); a2 = fmaf(wv[2][i4].w, h4.w, a2);
                a3 = fmaf(wv[3][i4].x, h4.x, a3); a3 = fmaf(wv[3][i4].y, h4.y, a3);
                a3 = fmaf(wv[3][i4].z, h4.z, a3); a3 = fmaf(wv[3][i4].w, h4.w, a3);
            }
            // reduce over ks (lane bits 2..5)
            a0 += __shfl_xor(a0, 4);  a1 += __shfl_xor(a1, 4);
            a2 += __shfl_xor(a2, 4);  a3 += __shfl_xor(a3, 4);
            a0 += __shfl_xor(a0, 8);  a1 += __shfl_xor(a1, 8);
            a2 += __shfl_xor(a2, 8);  a3 += __shfl_xor(a3, 8);
            a0 += __shfl_xor(a0, 16); a1 += __shfl_xor(a1, 16);
            a2 += __shfl_xor(a2, 16); a3 += __shfl_xor(a3, 16);
            a0 += __shfl_xor(a0, 32); a1 += __shfl_xor(a1, 32);
            a2 += __shfl_xor(a2, 32); a3 += __shfl_xor(a3, 32);
            // gather gates to owner lanes (lanes 4b..4b+3), transcendentals
            // ONLY on owners (4 active lanes per b)
            const int base = 4 * b;
            float gi_ = 0.f, gf_ = 0.f, gg_ = 0.f, go_ = 0.f;
#pragma unroll
            for (int jj = 0; jj < 4; jj++) {
                float a = (jj == 0) ? a0 : (jj == 1) ? a1 : (jj == 2) ? a2 : a3;
                float g0 = __shfl(a, base + 0);
                float g1 = __shfl(a, base + 1);
                float g2 = __shfl(a, base + 2);
                float g3 = __shfl(a, base + 3);
                if (lane == base + jj) { gi_ = g0; gf_ = g1; gg_ = g2; go_ = g3; }
            }
            if ((lane >> 2) == b) {
                float i_ = sigmoidf_(gi_), f_ = sigmoidf_(gf_);
                float G_ = tanh_fast(gg_), o_ = sigmoidf_(go_);
                c_ = f_ * c_ + i_ * G_;
                hw_mine = o_ * tanh_fast(c_);
            }
        }
        // write h (sc1) + hout (normal); lanes 0..31: (b=lane>>2, jj=lane&3)
        if (lane < 32) {
            int b = lane >> 2, jj = lane & 3, j = jq + jj;
            __hip_atomic_store(hb + (t & 1) * 4096 + b * HH + j, hw_mine,
                               __ATOMIC_RELAXED, __HIP_MEMORY_SCOPE_AGENT);
            hout[(size_t)(b * T + te) * HH + j] = hw_mine;
        }
        __builtin_amdgcn_s_waitcnt(0);           // h stores acked at coherence pt
        __syncthreads();                         // all 4 waves' stores done
        const int need = t + 1;
        if (threadIdx.x == 0)
            __hip_atomic_store(syn + wgi * 64, need, __ATOMIC_RELAXED, __HIP_MEMORY_SCOPE_AGENT);
        if (wgi == 0) {
            if (wave == 0) {
                int it = 0;
                while (true) {
                    int v = (lane < 32)
                        ? __hip_atomic_load(syn + lane * 64, __ATOMIC_RELAXED, __HIP_MEMORY_SCOPE_AGENT)
                        : need;
                    unsigned long long mset = __ballot(v >= need);
                    if ((mset & 0xFFFFFFFFull) == 0xFFFFFFFFull) break;
                    __builtin_amdgcn_s_sleep(2);
                    if (++it > (1 << 24)) break; // safety valve
                }
                if (lane == 0)
                    __hip_atomic_store(syn + 2048, need, __ATOMIC_RELAXED, __HIP_MEMORY_SCOPE_AGENT);
            }
        } else {
            if (threadIdx.x == 0) {
                int it = 0;
                while (__hip_atomic_load(syn + 2048, __ATOMIC_RELAXED, __HIP_MEMORY_SCOPE_AGENT) < need) {
                    __builtin_amdgcn_s_sleep(2);
                    if (++it > (1 << 24)) break; // safety valve
                }
            }
        }
        __syncthreads();
    }
}

__global__ __launch_bounds__(256) void cat_kernel(const float* hf, const float* hb, float* cat) {
    int i = blockIdx.x * 256 + threadIdx.x;      // over 2048*1024
    int row = i >> 10, h = i & 1023;
    cat[i] = (h < HH) ? hf[(size_t)row * HH + h] : hb[(size_t)row * HH + h - HH];
}

__global__ __launch_bounds__(256) void dur3_kernel(const float* __restrict__ h2,
                                                   const float* __restrict__ w,
                                                   const float* __restrict__ b, float* out) {
    int row = blockIdx.x * 256 + threadIdx.x;    // 2048
    float acc = b[0];
    const float* hp = h2 + (size_t)row * 256;
    for (int k = 0; k < 256; k++) acc += hp[k] * w[k];
    out[row] = acc;
}

// durations -> cumsum -> searchsorted index per mel position (-1 = pad)
__global__ __launch_bounds__(256) void length_reg_kernel(const float* __restrict__ dur, int* kidx) {
    int b = blockIdx.x;
    int t = threadIdx.x;
    __shared__ int cum[256];
    cum[t] = (int)rintf(dur[b * TT + t]);
    __syncthreads();
    for (int off = 1; off < 256; off <<= 1) {
        int val = (t >= off) ? cum[t - off] : 0;
        __syncthreads();
        cum[t] += val;
        __syncthreads();
    }
    int total = cum[255];
    for (int pos = t; pos < TM; pos += 256) {
        int lo = 0, hi = 256;
        while (lo < hi) {
            int mid = (lo + hi) >> 1;
            if (cum[mid] <= pos) lo = mid + 1; else hi = mid;
        }
        int idx = (pos < total) ? ((lo < 255) ? lo : 255) : -1;
        kidx[b * TM + pos] = idx;
    }
}

__global__ __launch_bounds__(256) void expand_kernel(const float* __restrict__ enc,
                                                     const int* __restrict__ kidx, float* exp_) {
    int i = blockIdx.x * 256 + threadIdx.x;      // over 8192*512
    int row = i >> 9, h = i & 511;               // row = b*1024 + pos
    int b = row >> 10;
    int id = kidx[row];
    exp_[i] = (id >= 0) ? enc[(size_t)(b * TT + id) * HH + h] : 0.f;
}

__global__ __launch_bounds__(256) void melin_kernel(const float* __restrict__ mel, float* mel_in) {
    int i = blockIdx.x * 256 + threadIdx.x;      // over 8192*80
    if (i >= BB * TM * MELC) return;
    int row = i / MELC, cc = i - row * MELC;
    int b = row >> 10, tpos = row & 1023;
    mel_in[i] = (tpos == 0) ? 0.f : mel[(size_t)(b * TM + tpos - 1) * MELC + cc];
}

// Flash-style MHA: one q-row per thread; K/V tiles (32x64) in LDS.
__global__ __launch_bounds__(256) void attn_kernel(const float* __restrict__ q,
                                                   const float* __restrict__ k,
                                                   const float* __restrict__ v,
                                                   const int* __restrict__ kidx,
                                                   float* __restrict__ ctx) {
    const int bh = blockIdx.y;
    const int b = bh >> 3, h = bh & 7;
    const int qrow = blockIdx.x * 256 + threadIdx.x;
    __shared__ float Ks[32][64];
    __shared__ float Vs[32][64];
    __shared__ float spad[32];

    float qr[64], acc[64];
    const float* qp = q + (size_t)(b * TM + qrow) * HH + h * 64;
#pragma unroll
    for (int d = 0; d < 64; d++) qr[d] = qp[d] * 0.125f;
#pragma unroll
    for (int d = 0; d < 64; d++) acc[d] = 0.f;
    float m = -1e30f, l = 0.f;

    for (int k0 = 0; k0 < TM; k0 += 32) {
        __syncthreads();
#pragma unroll
        for (int i = 0; i < 8; i++) {
            int idx = threadIdx.x + i * 256;     // 0..2047
            int r = idx >> 6, d = idx & 63;
            size_t off = (size_t)(b * TM + k0 + r) * HH + h * 64 + d;
            Ks[r][d] = k[off];
            Vs[r][d] = v[off];
        }
        if (threadIdx.x < 32)
            spad[threadIdx.x] = (kidx[b * TM + k0 + threadIdx.x] < 0) ? 1.f : 0.f;
        __syncthreads();
        for (int r = 0; r < 32; r++) {
            float s = 0.f;
#pragma unroll
            for (int d = 0; d < 64; d++) s += qr[d] * Ks[r][d];
            if (spad[r] != 0.f) s = -1e9f;
            float mn = fmaxf(m, s);
            float corr = __expf(m - mn);
            float p = __expf(s - mn);
            l = l * corr + p;
#pragma unroll
            for (int d = 0; d < 64; d++) acc[d] = acc[d] * corr + p * Vs[r][d];
            m = mn;
        }
    }
    float inv = 1.f / l;
    float* op = ctx + (size_t)(b * TM + qrow) * HH + h * 64;
#pragma unroll
    for (int d = 0; d < 64; d++) op[d] = acc[d] * inv;
}

__global__ __launch_bounds__(256) void decin_kernel(const float* q_in, const float* att, float* dec_in) {
    int i = blockIdx.x * 256 + threadIdx.x;      // over 8192*1024
    int row = i >> 10, h = i & 1023;
    dec_in[i] = (h < HH) ? q_in[(size_t)row * HH + h] : att[(size_t)row * HH + h - HH];
}

__global__ __launch_bounds__(256) void finalize_kernel(const float* melf, const float* logdur, float* out) {
    int i = blockIdx.x * 256 + threadIdx.x;
    if (i < BB * TM * MELC) out[i] = melf[i];
    else if (i < BB * TM * MELC + BB * TT) out[i] = logdur[i - BB * TM * MELC];
}

// ---------------------------------------------------------------------------
extern "C" void kernel_launch(void* const* d_in, const int* in_sizes, int n_in,
                              void* d_out, int out_size, void* d_ws, size_t ws_size,
                              hipStream_t stream) {
    const int*   ph      = (const int*)d_in[0];
    const float* mel     = (const float*)d_in[1];
    const float* durs    = (const float*)d_in[2];
    const float* emb     = (const float*)d_in[3];
    const float* w_ih_f  = (const float*)d_in[4];
    const float* w_hh_f  = (const float*)d_in[5];
    const float* b_ih_f  = (const float*)d_in[6];
    const float* b_hh_f  = (const float*)d_in[7];
    const float* w_ih_b  = (const float*)d_in[8];
    const float* w_hh_b  = (const float*)d_in[9];
    const float* b_ih_b  = (const float*)d_in[10];
    const float* b_hh_b  = (const float*)d_in[11];
    const float* proj_w  = (const float*)d_in[12];
    const float* proj_b  = (const float*)d_in[13];
    const float* dur_w1  = (const float*)d_in[14];
    const float* dur_b1  = (const float*)d_in[15];
    const float* dur_w2  = (const float*)d_in[16];
    const float* dur_b2  = (const float*)d_in[17];
    const float* dur_w3  = (const float*)d_in[18];
    const float* dur_b3  = (const float*)d_in[19];
    const float* melin_w = (const float*)d_in[20];
    const float* melin_b = (const float*)d_in[21];
    const float* attin_w = (const float*)d_in[22];
    const float* attin_b = (const float*)d_in[23];
    const float* atout_w = (const float*)d_in[24];
    const float* atout_b = (const float*)d_in[25];
    const float* dec_wih = (const float*)d_in[26];
    const float* dec_whh = (const float*)d_in[27];
    const float* dec_bih = (const float*)d_in[28];
    const float* dec_bhh = (const float*)d_in[29];
    const float* melo_w  = (const float*)d_in[30];
    const float* melo_b  = (const float*)d_in[31];

    float* ws = (float*)d_ws;
    int*   kidx = (int*)(ws + O_KIDX);
    int*   cnts = (int*)(ws + O_CNT);

    dim3 b256(256);
    auto gemm = [&](const float* A, const float* W, const float* bias, float* C,
                    int M, int N, int K, int act) {
        dim3 g((N + 127) / 128, (M + 127) / 128);
        if (act) gemm_bt<1><<<g, b256, 0, stream>>>(A, W, bias, C, M, N, K);
        else     gemm_bt<0><<<g, b256, 0, stream>>>(A, W, bias, C, M, N, K);
    };

    // 0) zero scan h-buffers + sync region (ws is poisoned each call)
    zero_kernel<<<144, b256, 0, stream>>>(ws, 36864);

    // 1) embedding -> x [2048,512]
    embed_kernel<<<(2048 * 512) / 256, b256, 0, stream>>>(ph, emb, ws + O_X);

    // 2) encoder xg = x@W_ih^T + b_ih  [2048,2048] per dir
    gemm(ws + O_X, w_ih_f, b_ih_f, ws + O_XGF, 2048, G4, HH, 0);
    gemm(ws + O_X, w_ih_b, b_ih_b, ws + O_XGB, 2048, G4, HH, 0);

    // 3) encoder scans: fwd+bwd in ONE persistent launch (64 wgs, 2 groups)
    lstm_scan<<<64, b256, 0, stream>>>(ws + O_XGF, ws + O_XGB,
                                       w_hh_f, w_hh_b, b_hh_f, b_hh_b,
                                       ws + O_ENCH, ws + O_HF, ws + O_HB,
                                       cnts, TT, 2);

    // 4) proj([hf,hb]) -> enc [2048,512]
    cat_kernel<<<(2048 * 1024) / 256, b256, 0, stream>>>(ws + O_HF, ws + O_HB, ws + O_CAT);
    gemm(ws + O_CAT, proj_w, proj_b, ws + O_ENC, 2048, HH, 2 * HH, 0);

    // 5) duration predictor
    gemm(ws + O_ENC, dur_w1, dur_b1, ws + O_H1, 2048, HH, HH, 1);
    gemm(ws + O_H1, dur_w2, dur_b2, ws + O_H2, 2048, 256, HH, 1);
    dur3_kernel<<<8, b256, 0, stream>>>(ws + O_H2, dur_w3, dur_b3, ws + O_LOGDUR);

    // 6) length regulation
    length_reg_kernel<<<8, b256, 0, stream>>>(durs, kidx);
    expand_kernel<<<(8192 * 512) / 256, b256, 0, stream>>>(ws + O_ENC, kidx, ws + O_EXP);

    // 7) q_in = Linear(mel shifted) [8192,512]
    melin_kernel<<<(8192 * MELC + 255) / 256, b256, 0, stream>>>(mel, ws + O_MELIN);
    gemm(ws + O_MELIN, melin_w, melin_b, ws + O_QIN, 8192, HH, MELC, 0);

    // 8) q,k,v projections (attn_in_w rows: [wq;wk;wv])
    gemm(ws + O_QIN, attin_w,              attin_b,        ws + O_Q, 8192, HH, HH, 0);
    gemm(ws + O_EXP, attin_w + 512 * 512,  attin_b + 512,  ws + O_K, 8192, HH, HH, 0);
    gemm(ws + O_EXP, attin_w + 1024 * 512, attin_b + 1024, ws + O_V, 8192, HH, HH, 0);

    // 9) attention -> ctx; out projection -> attended
    attn_kernel<<<dim3(4, 64), b256, 0, stream>>>(ws + O_Q, ws + O_K, ws + O_V, kidx, ws + O_CTX);
    gemm(ws + O_CTX, atout_w, atout_b, ws + O_ATT, 8192, HH, HH, 0);

    // 10) decoder: dec_in = [q_in, attended]; xg = dec_in@W_ih^T + b_ih
    decin_kernel<<<(8192 * 1024) / 256, b256, 0, stream>>>(ws + O_QIN, ws + O_ATT, ws + O_DECIN);
    gemm(ws + O_DECIN, dec_wih, dec_bih, ws + O_XGD, 8192, G4, 2 * HH, 0);

    // 11) decoder scan: ONE persistent launch (32 wgs)
    lstm_scan<<<32, b256, 0, stream>>>(ws + O_XGD, ws + O_XGD,
                                       dec_whh, dec_whh, dec_bhh, dec_bhh,
                                       ws + O_DECH, ws + O_HDEC, ws + O_HDEC,
                                       cnts + 8192, TM, 1);

    // 12) mel projection + pack outputs
    gemm(ws + O_HDEC, melo_w, melo_b, ws + O_MELF, 8192, MELC, HH, 0);
    finalize_kernel<<<(BB * TM * MELC + BB * TT + 255) / 256, b256, 0, stream>>>(
        ws + O_MELF, ws + O_LOGDUR, (float*)d_out);
}

// Round 7
// 15869.562 us; speedup vs baseline: 3.3035x; 1.0634x over previous
//
#include <hip/hip_runtime.h>

// ---------------------------------------------------------------------------
// KokoroModel: emb -> biLSTM enc -> proj -> dur MLP -> length-regulate ->
//              MHA (teacher-forced) -> dec LSTM -> mel proj
// B=8, T_TEXT=256, T_MEL=1024, H=512, MEL=80, NH=8, HD=64 — all fp32.
// Round 7: lstm_scan barrier flattened — no master/pub hop; each wg polls all
// 32 spread flags (ballot) directly. Next-step xg prefetch issued before the
// poll so HBM latency hides under the wait. Everything else as round 6.
// ---------------------------------------------------------------------------

typedef unsigned short u16;
typedef unsigned int u32;
typedef float f4 __attribute__((ext_vector_type(4)));

#define BB 8
#define TT 256
#define TM 1024
#define HH 512
#define MELC 80
#define G4 2048   // 4*H

__device__ __forceinline__ float sigmoidf_(float x) { return 1.f / (1.f + __expf(-x)); }
__device__ __forceinline__ float tanh_fast(float x) {
    float e = __expf(2.f * x);
    return 1.f - 2.f / (e + 1.f);
}

// ------------------------- workspace layout (floats) -----------------------
#define O_ENCH    0u
#define O_DECH    16384u
#define O_CNT     24576u            /* ints, 3*4096 = 12288 (ends at 36864) */
#define O_LOGDUR  36864u
#define O_KIDX    38912u            /* 8192 ints */
#define O_ENC     47104u            /* 2048x512 */
#define O_R1      1095680u          /* 4M: hf|hb|cat  -> exp -> ctx */
#define O_ATT     5289984u          /* 4M attended */
#define O_QIN     9484288u          /* 4M q_in */
#define O_BIG2    13678592u         /* 8M: q|k -> dec_in -> h_dec|mel_f */
#define O_BIG1    22067200u         /* 16.8M: xg_f|xg_b|x -> h1|h2|v|mel_in -> xg_dec */
// sub-offsets
#define O_HF      (O_R1)
#define O_HB      (O_R1 + 1048576u)
#define O_CAT     (O_R1 + 2097152u)
#define O_EXP     (O_R1)
#define O_CTX     (O_R1)
#define O_Q       (O_BIG2)
#define O_K       (O_BIG2 + 4194304u)
#define O_DECIN   (O_BIG2)
#define O_HDEC    (O_BIG2)
#define O_MELF    (O_BIG2 + 4194304u)
#define O_XGF     (O_BIG1)
#define O_XGB     (O_BIG1 + 4194304u)
#define O_X       (O_BIG1 + 8388608u)
#define O_H1      (O_BIG1 + 8388608u)
#define O_H2      (O_BIG1 + 9437184u)
#define O_V       (O_BIG1 + 10485760u)
#define O_MELIN   (O_BIG1 + 14680064u)
#define O_XGD     (O_BIG1)

// ---------------------------------------------------------------------------
__global__ __launch_bounds__(256) void zero_kernel(float* p, int n) {
    int i = blockIdx.x * 256 + threadIdx.x;
    if (i < n) p[i] = 0.f;
}

__global__ __launch_bounds__(256) void embed_kernel(const int* idx, const float* emb, float* x) {
    int i = blockIdx.x * 256 + threadIdx.x;      // over 2048*512
    int tok = i >> 9, h = i & 511;
    x[i] = emb[(size_t)idx[tok] * HH + h];
}

// C[M,N] = act(A[M,K] @ W[N,K]^T + bias[N]);  all fp32.
// 128x128 tile, BK=16, 256 threads, 8x8 micro-tile in 2x2 float4 fragments.
template <int ACT>
__global__ __launch_bounds__(256) void gemm_bt(const float* __restrict__ A,
                                               const float* __restrict__ W,
                                               const float* __restrict__ bias,
                                               float* __restrict__ C,
                                               int M, int N, int K) {
    __shared__ float As[16][132];
    __shared__ float Ws[16][132];
    const int bm = blockIdx.y * 128, bn = blockIdx.x * 128;
    const int tid = threadIdx.x;
    const int tx = tid & 15, ty = tid >> 4;
    float acc[64];
#pragma unroll
    for (int i = 0; i < 64; i++) acc[i] = 0.f;

    for (int k0 = 0; k0 < K; k0 += 16) {
#pragma unroll
        for (int q = 0; q < 2; q++) {
            int fid = tid * 2 + q;               // 0..511
            int m = fid >> 2, kq = (fid & 3) << 2;
            float4 va = *(const float4*)(A + (size_t)(bm + m) * K + k0 + kq);
            As[kq + 0][m] = va.x; As[kq + 1][m] = va.y;
            As[kq + 2][m] = va.z; As[kq + 3][m] = va.w;
            float4 vw = make_float4(0.f, 0.f, 0.f, 0.f);
            if (bn + m < N) vw = *(const float4*)(W + (size_t)(bn + m) * K + k0 + kq);
            Ws[kq + 0][m] = vw.x; Ws[kq + 1][m] = vw.y;
            Ws[kq + 2][m] = vw.z; Ws[kq + 3][m] = vw.w;
        }
        __syncthreads();
#pragma unroll
        for (int kk = 0; kk < 16; kk++) {
            float4 a0 = *(const float4*)&As[kk][ty * 4];
            float4 a1 = *(const float4*)&As[kk][64 + ty * 4];
            float4 b0 = *(const float4*)&Ws[kk][tx * 4];
            float4 b1 = *(const float4*)&Ws[kk][64 + tx * 4];
            float av[8] = {a0.x, a0.y, a0.z, a0.w, a1.x, a1.y, a1.z, a1.w};
            float bv[8] = {b0.x, b0.y, b0.z, b0.w, b1.x, b1.y, b1.z, b1.w};
#pragma unroll
            for (int ih = 0; ih < 2; ih++)
#pragma unroll
                for (int ii = 0; ii < 4; ii++) {
                    float a = av[ih * 4 + ii];
#pragma unroll
                    for (int jh = 0; jh < 2; jh++)
#pragma unroll
                        for (int jjv = 0; jjv < 4; jjv++)
                            acc[(ih * 2 + jh) * 16 + ii * 4 + jjv] =
                                fmaf(a, bv[jh * 4 + jjv], acc[(ih * 2 + jh) * 16 + ii * 4 + jjv]);
                }
        }
        __syncthreads();
    }
#pragma unroll
    for (int ih = 0; ih < 2; ih++)
#pragma unroll
        for (int jh = 0; jh < 2; jh++) {
            int n = bn + jh * 64 + tx * 4;
            if (n >= N) continue;
            float4 bb = make_float4(0.f, 0.f, 0.f, 0.f);
            if (bias) bb = *(const float4*)(bias + n);
#pragma unroll
            for (int ii = 0; ii < 4; ii++) {
                int m = bm + ih * 64 + ty * 4 + ii;
                float4 o;
                o.x = acc[(ih * 2 + jh) * 16 + ii * 4 + 0] + bb.x;
                o.y = acc[(ih * 2 + jh) * 16 + ii * 4 + 1] + bb.y;
                o.z = acc[(ih * 2 + jh) * 16 + ii * 4 + 2] + bb.z;
                o.w = acc[(ih * 2 + jh) * 16 + ii * 4 + 3] + bb.w;
                if (ACT == 1) {
                    o.x = fmaxf(o.x, 0.f); o.y = fmaxf(o.y, 0.f);
                    o.z = fmaxf(o.z, 0.f); o.w = fmaxf(o.w, 0.f);
                }
                *(float4*)(C + (size_t)m * N + n) = o;
            }
        }
}

// ---------------------------------------------------------------------------
// Persistent fence-free LSTM scan. 32 wgs/group; wg owns 16 j x 4 gates x all
// 8 batches; W_hh in VGPRs. h exchange: sc1 stores / dwordx4 sc0 sc1 staging.
// Barrier v3: flat all-to-all — after vmcnt0, each wg stores its spread flag;
// every wg's wave0 polls all 32 flags (ballot). Next-step xg loads issued
// before the poll to hide HBM latency under the wait.
__global__ __launch_bounds__(256, 1) void lstm_scan(
    const float* __restrict__ xg0, const float* __restrict__ xg1,
    const float* __restrict__ whh0, const float* __restrict__ whh1,
    const float* __restrict__ bhh0, const float* __restrict__ bhh1,
    float* hbuf, float* hout0, float* hout1,
    int* sync, int T, int ndir) {
    const int wg = blockIdx.x;
    const int group = wg >> 5;                   // dir (or 0)
    const int wgi = wg & 31;
    const int dir = (ndir == 2) ? group : 0;
    const float* xg  = dir ? xg1 : xg0;
    const float* whh = dir ? whh1 : whh0;
    const float* bhh = dir ? bhh1 : bhh0;
    float* hout = dir ? hout1 : hout0;
    float* hb = hbuf + group * 8192;             // [2 slots][8][512]
    int* syn = sync + group * 4096;              // flags at wgi*64

    const int wave = threadIdx.x >> 6;
    const int lane = threadIdx.x & 63;
    const int gate = lane & 3;
    const int ks = lane >> 2;                    // k-slice of 32
    const int jq = wgi * 16 + wave * 4;

    // weights: wv[jj][i4] = W_hh[gate*512 + jq+jj][ks*32 + i4*4 ..+4)
    float4 wv[4][8];
#pragma unroll
    for (int jj = 0; jj < 4; jj++) {
        const float4* wp = (const float4*)(whh + (size_t)(gate * HH + jq + jj) * HH + ks * 32);
#pragma unroll
        for (int i = 0; i < 8; i++) wv[jj][i] = wp[i];
    }
    float xb0 = bhh[gate * HH + jq + 0];
    float xb1 = bhh[gate * HH + jq + 1];
    float xb2 = bhh[gate * HH + jq + 2];
    float xb3 = bhh[gate * HH + jq + 3];
    float c_ = 0.f;                              // owner-lane cell state

    __shared__ float hs[4096];                   // staged h, bank-rotated

    // prefetch xg for t=0
    float4 xgv[8];
    if (ks == 0) {
        const int te0 = dir ? (T - 1) : 0;
#pragma unroll
        for (int b = 0; b < 8; b++)
            xgv[b] = *(const float4*)(xg + (size_t)(b * T + te0) * G4 + gate * HH + jq);
    }

    for (int t = 0; t < T; t++) {
        const int te = dir ? (T - 1 - t) : t;
        // stage h_prev: 4 x dwordx4 sc0 sc1 per thread -> LDS (bank-rotated)
        const float* hg = hb + ((t + 1) & 1) * 4096;
        f4 hv[4];
#pragma unroll
        for (int q = 0; q < 4; q++) {
            const float* ap = hg + ((q * 256 + threadIdx.x) << 2);
            asm volatile("global_load_dwordx4 %0, %1, off sc0 sc1"
                         : "=v"(hv[q]) : "v"(ap) : "memory");
        }
        __builtin_amdgcn_s_waitcnt(0);
#pragma unroll
        for (int q = 0; q < 4; q++) {
            int flat = (q * 256 + threadIdx.x) << 2;
            int bb = flat >> 9, kk = flat & 511;
            int blk = kk >> 5, off = kk & 31;
            *(f4*)&hs[bb * HH + blk * 32 + ((off + (blk << 2)) & 31)] = hv[q];
        }
        __syncthreads();

        float hw_mine = 0.f;
#pragma unroll
        for (int b = 0; b < 8; b++) {
            float a0, a1, a2, a3;
            if (ks == 0) {
                a0 = xgv[b].x + xb0; a1 = xgv[b].y + xb1;
                a2 = xgv[b].z + xb2; a3 = xgv[b].w + xb3;
            } else { a0 = a1 = a2 = a3 = 0.f; }
#pragma unroll
            for (int i4 = 0; i4 < 8; i4++) {
                const float4 h4 = *(const float4*)
                    &hs[b * HH + ks * 32 + (((i4 + ks) & 7) << 2)];
                a0 = fmaf(wv[0][i4].x, h4.x, a0); a0 = fmaf(wv[0][i4].y, h4.y, a0);
                a0 = fmaf(wv[0][i4].z, h4.z, a0); a0 = fmaf(wv[0][i4].w, h4.w, a0);
                a1 = fmaf(wv[1][i4].x, h4.x, a1); a1 = fmaf(wv[1][i4].y, h4.y, a1);
                a1 = fmaf(wv[1][i4].z, h4.z, a1); a1 = fmaf(wv[1][i4].w, h4.w, a1);
                a2 = fmaf(wv[2][i4].x, h4.x, a2); a2 = fmaf(wv[2][i4].y, h4.y, a2);
                a2 = fmaf(wv[2][i4].z, h4.z, a2); a2 = fmaf(wv[2][i4].w, h4.w, a2);
                a3 = fmaf(wv[3][i4].x, h4.x, a3); a3 = fmaf(wv[3][i4].y, h4.y, a3);
                a3 = fmaf(wv[3][i4].z, h4.z, a3); a3 = fmaf(wv[3][i4].w, h4.w, a3);
            }
            // reduce over ks (lane bits 2..5)
            a0 += __shfl_xor(a0, 4);  a1 += __shfl_xor(a1, 4);
            a2 += __shfl_xor(a2, 4);  a3 += __shfl_xor(a3, 4);
            a0 += __shfl_xor(a0, 8);  a1 += __shfl_xor(a1, 8);
            a2 += __shfl_xor(a2, 8);  a3 += __shfl_xor(a3, 8);
            a0 += __shfl_xor(a0, 16); a1 += __shfl_xor(a1, 16);
            a2 += __shfl_xor(a2, 16); a3 += __shfl_xor(a3, 16);
            a0 += __shfl_xor(a0, 32); a1 += __shfl_xor(a1, 32);
            a2 += __shfl_xor(a2, 32); a3 += __shfl_xor(a3, 32);
            // gather gates to owner lanes (lanes 4b..4b+3)
            const int base = 4 * b;
            float gi_ = 0.f, gf_ = 0.f, gg_ = 0.f, go_ = 0.f;
#pragma unroll
            for (int jj = 0; jj < 4; jj++) {
                float a = (jj == 0) ? a0 : (jj == 1) ? a1 : (jj == 2) ? a2 : a3;
                float g0 = __shfl(a, base + 0);
                float g1 = __shfl(a, base + 1);
                float g2 = __shfl(a, base + 2);
                float g3 = __shfl(a, base + 3);
                if (lane == base + jj) { gi_ = g0; gf_ = g1; gg_ = g2; go_ = g3; }
            }
            if ((lane >> 2) == b) {
                float i_ = sigmoidf_(gi_), f_ = sigmoidf_(gf_);
                float G_ = tanh_fast(gg_), o_ = sigmoidf_(go_);
                c_ = f_ * c_ + i_ * G_;
                hw_mine = o_ * tanh_fast(c_);
            }
        }
        // write h (sc1) + hout (normal); lanes 0..31: (b=lane>>2, jj=lane&3)
        if (lane < 32) {
            int b = lane >> 2, jj = lane & 3, j = jq + jj;
            __hip_atomic_store(hb + (t & 1) * 4096 + b * HH + j, hw_mine,
                               __ATOMIC_RELAXED, __HIP_MEMORY_SCOPE_AGENT);
            hout[(size_t)(b * T + te) * HH + j] = hw_mine;
        }
        __builtin_amdgcn_s_waitcnt(0);           // h stores acked at coherence pt
        __syncthreads();                         // all 4 waves' stores done
        const int need = t + 1;
        if (threadIdx.x == 0)
            __hip_atomic_store(syn + wgi * 64, need, __ATOMIC_RELAXED, __HIP_MEMORY_SCOPE_AGENT);
        // prefetch next step's xg while waiting on the barrier
        if (ks == 0 && t + 1 < T) {
            const int teN = dir ? (T - 2 - t) : (t + 1);
#pragma unroll
            for (int b = 0; b < 8; b++)
                xgv[b] = *(const float4*)(xg + (size_t)(b * T + teN) * G4 + gate * HH + jq);
        }
        // flat all-to-all: wave0 polls all 32 spread flags
        if (wave == 0) {
            int it = 0;
            while (true) {
                int v = (lane < 32)
                    ? __hip_atomic_load(syn + lane * 64, __ATOMIC_RELAXED, __HIP_MEMORY_SCOPE_AGENT)
                    : need;
                unsigned long long mset = __ballot(v >= need);
                if ((mset & 0xFFFFFFFFull) == 0xFFFFFFFFull) break;
                __builtin_amdgcn_s_sleep(1);
                if (++it > (1 << 24)) break;     // safety valve
            }
        }
        __syncthreads();
    }
}

__global__ __launch_bounds__(256) void cat_kernel(const float* hf, const float* hb, float* cat) {
    int i = blockIdx.x * 256 + threadIdx.x;      // over 2048*1024
    int row = i >> 10, h = i & 1023;
    cat[i] = (h < HH) ? hf[(size_t)row * HH + h] : hb[(size_t)row * HH + h - HH];
}

__global__ __launch_bounds__(256) void dur3_kernel(const float* __restrict__ h2,
                                                   const float* __restrict__ w,
                                                   const float* __restrict__ b, float* out) {
    int row = blockIdx.x * 256 + threadIdx.x;    // 2048
    float acc = b[0];
    const float* hp = h2 + (size_t)row * 256;
    for (int k = 0; k < 256; k++) acc += hp[k] * w[k];
    out[row] = acc;
}

// durations -> cumsum -> searchsorted index per mel position (-1 = pad)
__global__ __launch_bounds__(256) void length_reg_kernel(const float* __restrict__ dur, int* kidx) {
    int b = blockIdx.x;
    int t = threadIdx.x;
    __shared__ int cum[256];
    cum[t] = (int)rintf(dur[b * TT + t]);
    __syncthreads();
    for (int off = 1; off < 256; off <<= 1) {
        int val = (t >= off) ? cum[t - off] : 0;
        __syncthreads();
        cum[t] += val;
        __syncthreads();
    }
    int total = cum[255];
    for (int pos = t; pos < TM; pos += 256) {
        int lo = 0, hi = 256;
        while (lo < hi) {
            int mid = (lo + hi) >> 1;
            if (cum[mid] <= pos) lo = mid + 1; else hi = mid;
        }
        int idx = (pos < total) ? ((lo < 255) ? lo : 255) : -1;
        kidx[b * TM + pos] = idx;
    }
}

__global__ __launch_bounds__(256) void expand_kernel(const float* __restrict__ enc,
                                                     const int* __restrict__ kidx, float* exp_) {
    int i = blockIdx.x * 256 + threadIdx.x;      // over 8192*512
    int row = i >> 9, h = i & 511;               // row = b*1024 + pos
    int b = row >> 10;
    int id = kidx[row];
    exp_[i] = (id >= 0) ? enc[(size_t)(b * TT + id) * HH + h] : 0.f;
}

__global__ __launch_bounds__(256) void melin_kernel(const float* __restrict__ mel, float* mel_in) {
    int i = blockIdx.x * 256 + threadIdx.x;      // over 8192*80
    if (i >= BB * TM * MELC) return;
    int row = i / MELC, cc = i - row * MELC;
    int b = row >> 10, tpos = row & 1023;
    mel_in[i] = (tpos == 0) ? 0.f : mel[(size_t)(b * TM + tpos - 1) * MELC + cc];
}

// Flash-style MHA: one q-row per thread; K/V tiles (32x64) in LDS.
__global__ __launch_bounds__(256) void attn_kernel(const float* __restrict__ q,
                                                   const float* __restrict__ k,
                                                   const float* __restrict__ v,
                                                   const int* __restrict__ kidx,
                                                   float* __restrict__ ctx) {
    const int bh = blockIdx.y;
    const int b = bh >> 3, h = bh & 7;
    const int qrow = blockIdx.x * 256 + threadIdx.x;
    __shared__ float Ks[32][64];
    __shared__ float Vs[32][64];
    __shared__ float spad[32];

    float qr[64], acc[64];
    const float* qp = q + (size_t)(b * TM + qrow) * HH + h * 64;
#pragma unroll
    for (int d = 0; d < 64; d++) qr[d] = qp[d] * 0.125f;
#pragma unroll
    for (int d = 0; d < 64; d++) acc[d] = 0.f;
    float m = -1e30f, l = 0.f;

    for (int k0 = 0; k0 < TM; k0 += 32) {
        __syncthreads();
#pragma unroll
        for (int i = 0; i < 8; i++) {
            int idx = threadIdx.x + i * 256;     // 0..2047
            int r = idx >> 6, d = idx & 63;
            size_t off = (size_t)(b * TM + k0 + r) * HH + h * 64 + d;
            Ks[r][d] = k[off];
            Vs[r][d] = v[off];
        }
        if (threadIdx.x < 32)
            spad[threadIdx.x] = (kidx[b * TM + k0 + threadIdx.x] < 0) ? 1.f : 0.f;
        __syncthreads();
        for (int r = 0; r < 32; r++) {
            float s = 0.f;
#pragma unroll
            for (int d = 0; d < 64; d++) s += qr[d] * Ks[r][d];
            if (spad[r] != 0.f) s = -1e9f;
            float mn = fmaxf(m, s);
            float corr = __expf(m - mn);
            float p = __expf(s - mn);
            l = l * corr + p;
#pragma unroll
            for (int d = 0; d < 64; d++) acc[d] = acc[d] * corr + p * Vs[r][d];
            m = mn;
        }
    }
    float inv = 1.f / l;
    float* op = ctx + (size_t)(b * TM + qrow) * HH + h * 64;
#pragma unroll
    for (int d = 0; d < 64; d++) op[d] = acc[d] * inv;
}

__global__ __launch_bounds__(256) void decin_kernel(const float* q_in, const float* att, float* dec_in) {
    int i = blockIdx.x * 256 + threadIdx.x;      // over 8192*1024
    int row = i >> 10, h = i & 1023;
    dec_in[i] = (h < HH) ? q_in[(size_t)row * HH + h] : att[(size_t)row * HH + h - HH];
}

__global__ __launch_bounds__(256) void finalize_kernel(const float* melf, const float* logdur, float* out) {
    int i = blockIdx.x * 256 + threadIdx.x;
    if (i < BB * TM * MELC) out[i] = melf[i];
    else if (i < BB * TM * MELC + BB * TT) out[i] = logdur[i - BB * TM * MELC];
}

// ---------------------------------------------------------------------------
extern "C" void kernel_launch(void* const* d_in, const int* in_sizes, int n_in,
                              void* d_out, int out_size, void* d_ws, size_t ws_size,
                              hipStream_t stream) {
    const int*   ph      = (const int*)d_in[0];
    const float* mel     = (const float*)d_in[1];
    const float* durs    = (const float*)d_in[2];
    const float* emb     = (const float*)d_in[3];
    const float* w_ih_f  = (const float*)d_in[4];
    const float* w_hh_f  = (const float*)d_in[5];
    const float* b_ih_f  = (const float*)d_in[6];
    const float* b_hh_f  = (const float*)d_in[7];
    const float* w_ih_b  = (const float*)d_in[8];
    const float* w_hh_b  = (const float*)d_in[9];
    const float* b_ih_b  = (const float*)d_in[10];
    const float* b_hh_b  = (const float*)d_in[11];
    const float* proj_w  = (const float*)d_in[12];
    const float* proj_b  = (const float*)d_in[13];
    const float* dur_w1  = (const float*)d_in[14];
    const float* dur_b1  = (const float*)d_in[15];
    const float* dur_w2  = (const float*)d_in[16];
    const float* dur_b2  = (const float*)d_in[17];
    const float* dur_w3  = (const float*)d_in[18];
    const float* dur_b3  = (const float*)d_in[19];
    const float* melin_w = (const float*)d_in[20];
    const float* melin_b = (const float*)d_in[21];
    const float* attin_w = (const float*)d_in[22];
    const float* attin_b = (const float*)d_in[23];
    const float* atout_w = (const float*)d_in[24];
    const float* atout_b = (const float*)d_in[25];
    const float* dec_wih = (const float*)d_in[26];
    const float* dec_whh = (const float*)d_in[27];
    const float* dec_bih = (const float*)d_in[28];
    const float* dec_bhh = (const float*)d_in[29];
    const float* melo_w  = (const float*)d_in[30];
    const float* melo_b  = (const float*)d_in[31];

    float* ws = (float*)d_ws;
    int*   kidx = (int*)(ws + O_KIDX);
    int*   cnts = (int*)(ws + O_CNT);

    dim3 b256(256);
    auto gemm = [&](const float* A, const float* W, const float* bias, float* C,
                    int M, int N, int K, int act) {
        dim3 g((N + 127) / 128, (M + 127) / 128);
        if (act) gemm_bt<1><<<g, b256, 0, stream>>>(A, W, bias, C, M, N, K);
        else     gemm_bt<0><<<g, b256, 0, stream>>>(A, W, bias, C, M, N, K);
    };

    // 0) zero scan h-buffers + sync region (ws is poisoned each call)
    zero_kernel<<<144, b256, 0, stream>>>(ws, 36864);

    // 1) embedding -> x [2048,512]
    embed_kernel<<<(2048 * 512) / 256, b256, 0, stream>>>(ph, emb, ws + O_X);

    // 2) encoder xg = x@W_ih^T + b_ih  [2048,2048] per dir
    gemm(ws + O_X, w_ih_f, b_ih_f, ws + O_XGF, 2048, G4, HH, 0);
    gemm(ws + O_X, w_ih_b, b_ih_b, ws + O_XGB, 2048, G4, HH, 0);

    // 3) encoder scans: fwd+bwd in ONE persistent launch (64 wgs, 2 groups)
    lstm_scan<<<64, b256, 0, stream>>>(ws + O_XGF, ws + O_XGB,
                                       w_hh_f, w_hh_b, b_hh_f, b_hh_b,
                                       ws + O_ENCH, ws + O_HF, ws + O_HB,
                                       cnts, TT, 2);

    // 4) proj([hf,hb]) -> enc [2048,512]
    cat_kernel<<<(2048 * 1024) / 256, b256, 0, stream>>>(ws + O_HF, ws + O_HB, ws + O_CAT);
    gemm(ws + O_CAT, proj_w, proj_b, ws + O_ENC, 2048, HH, 2 * HH, 0);

    // 5) duration predictor
    gemm(ws + O_ENC, dur_w1, dur_b1, ws + O_H1, 2048, HH, HH, 1);
    gemm(ws + O_H1, dur_w2, dur_b2, ws + O_H2, 2048, 256, HH, 1);
    dur3_kernel<<<8, b256, 0, stream>>>(ws + O_H2, dur_w3, dur_b3, ws + O_LOGDUR);

    // 6) length regulation
    length_reg_kernel<<<8, b256, 0, stream>>>(durs, kidx);
    expand_kernel<<<(8192 * 512) / 256, b256, 0, stream>>>(ws + O_ENC, kidx, ws + O_EXP);

    // 7) q_in = Linear(mel shifted) [8192,512]
    melin_kernel<<<(8192 * MELC + 255) / 256, b256, 0, stream>>>(mel, ws + O_MELIN);
    gemm(ws + O_MELIN, melin_w, melin_b, ws + O_QIN, 8192, HH, MELC, 0);

    // 8) q,k,v projections (attn_in_w rows: [wq;wk;wv])
    gemm(ws + O_QIN, attin_w,              attin_b,        ws + O_Q, 8192, HH, HH, 0);
    gemm(ws + O_EXP, attin_w + 512 * 512,  attin_b + 512,  ws + O_K, 8192, HH, HH, 0);
    gemm(ws + O_EXP, attin_w + 1024 * 512, attin_b + 1024, ws + O_V, 8192, HH, HH, 0);

    // 9) attention -> ctx; out projection -> attended
    attn_kernel<<<dim3(4, 64), b256, 0, stream>>>(ws + O_Q, ws + O_K, ws + O_V, kidx, ws + O_CTX);
    gemm(ws + O_CTX, atout_w, atout_b, ws + O_ATT, 8192, HH, HH, 0);

    // 10) decoder: dec_in = [q_in, attended]; xg = dec_in@W_ih^T + b_ih
    decin_kernel<<<(8192 * 1024) / 256, b256, 0, stream>>>(ws + O_QIN, ws + O_ATT, ws + O_DECIN);
    gemm(ws + O_DECIN, dec_wih, dec_bih, ws + O_XGD, 8192, G4, 2 * HH, 0);

    // 11) decoder scan: ONE persistent launch (32 wgs)
    lstm_scan<<<32, b256, 0, stream>>>(ws + O_XGD, ws + O_XGD,
                                       dec_whh, dec_whh, dec_bhh, dec_bhh,
                                       ws + O_DECH, ws + O_HDEC, ws + O_HDEC,
                                       cnts + 8192, TM, 1);

    // 12) mel projection + pack outputs
    gemm(ws + O_HDEC, melo_w, melo_b, ws + O_MELF, 8192, MELC, HH, 0);
    finalize_kernel<<<(BB * TM * MELC + BB * TT + 255) / 256, b256, 0, stream>>>(
        ws + O_MELF, ws + O_LOGDUR, (float*)d_out);
}